// Round 20
// baseline (283.498 us; speedup 1.0000x reference)
//
#include <hip/hip_runtime.h>
#include <hip/hip_bf16.h>
#include <cstddef>

#define BBn  2
#define CCn  256
#define HHn  128
#define WWn  128
#define NNn  (HHn*WWn)        // 16384
#define MTOT (BBn*NNn)        // 32768
#define PADW 130

typedef unsigned short u16;
typedef __attribute__((ext_vector_type(8))) short bf8v;
typedef __attribute__((ext_vector_type(8))) unsigned short u16x8;
typedef __attribute__((ext_vector_type(4))) float f4v;

typedef __attribute__((address_space(1))) const void gvoid_t;
typedef __attribute__((address_space(3))) void svoid_t;
#define ASYNC16(g, l) __builtin_amdgcn_global_load_lds((gvoid_t*)(g), (svoid_t*)(l), 16, 0, 0)

__device__ __forceinline__ u16 f2bf(float f) {
    __hip_bfloat16 h = __float2bfloat16(f);
    return *reinterpret_cast<u16*>(&h);
}
__device__ __forceinline__ float bf2f(u16 h) {
    return __uint_as_float(((unsigned)h) << 16);
}

// z-offsets (elements), applied scaled by blockIdx.z
struct ZOff {
    long a, w, bia, f1, f2, b1, r, p;
    int ch;
};

// ---------------------------------------------------------------------------
// bf16 MFMA GEMM, tile BM x BN, BK=32, double-buffered LDS (stage-ahead),
// both-sides XOR swizzle: chunk' = chunk ^ ((row>>1)&3).
// EPI: 4 sigmoid-gate (bf16 out) | 5 ReLU->bf16
//      7 resid(bf16)-init + rowLN -> pad bf16
//      9 resid(bf16)-init + rowLN -> (B,C,N) + cam, LDS-transposed coalesced
// ---------------------------------------------------------------------------
template<int BM, int BN, int WC, int EPI, int KK>
__global__ __launch_bounds__(256)
void mgemm(const u16* __restrict__ A, const u16* __restrict__ Wt,
           const float* __restrict__ bias, int ldw, int Nc,
           float* __restrict__ outf, float* __restrict__ outf2,
           u16* __restrict__ outb, const u16* __restrict__ img,
           const void* __restrict__ resid,
           const float* __restrict__ p0, const float* __restrict__ p1,
           int choff, ZOff zo)
{
    constexpr int WR = 4 / WC;
    constexpr int MROWS = BM / WR;       // rows per wave
    constexpr int MI = MROWS / 16;
    constexpr int AT = BM / 64;          // A staging chunks per thread
    constexpr int BT = BN / 64;
    constexpr int NSTEPS = KK / 32;

    __shared__ __align__(16) u16 As[2 * BM * 32];
    __shared__ __align__(16) u16 Bs[2 * BN * 32];
    __shared__ float red[4][64][2];      // LN cross-wave partials (EPI 7/9)

    const int z = blockIdx.z;
    if (z) {
        A += (long)z * zo.a; Wt += (long)z * zo.w;
        if (bias)  bias  += (long)z * zo.bia;
        if (outf)  outf  += (long)z * zo.f1;
        if (outf2) outf2 += (long)z * zo.f2;
        if (outb)  outb  += (long)z * zo.b1;
        if (p0)    p0    += (long)z * zo.p;
        if (p1)    p1    += (long)z * zo.p;
        choff += z * zo.ch;
    }

    const int tid  = threadIdx.x;
    const int lane = tid & 63;
    const int w    = tid >> 6;
    const int wr   = w / WC, wc = w % WC;
    const int by = blockIdx.y;
    const int m0 = by * BM;
    const int n0 = blockIdx.x * BN;
    const int lr = lane & 15, lq = lane >> 4;

    // staging source pointers (source chunk pre-swizzled; LDS dest linear)
    const u16* gA[AT]; int loA[AT];
    #pragma unroll
    for (int t = 0; t < AT; ++t) {
        int c = t * 256 + tid; int row = c >> 2; int part = c & 3;
        int pg = part ^ ((row >> 1) & 3);
        gA[t] = A + (size_t)(m0 + row) * KK + pg * 8;
        loA[t] = c * 8;
    }
    const u16* gB[BT]; int loB[BT];
    #pragma unroll
    for (int t = 0; t < BT; ++t) {
        int c = t * 256 + tid; int row = c >> 2; int part = c & 3;
        int pg = part ^ ((row >> 1) & 3);
        gB[t] = Wt + (size_t)(n0 + row) * ldw + pg * 8;
        loB[t] = c * 8;
    }

    // accumulator (residual+bias init for LN epilogues; WR==1 there)
    f4v acc[MI][4];
    if constexpr (EPI == 7 || EPI == 9) {
        const u16* r16 = (const u16*)resid + (EPI == 7 ? (long)z * zo.r : 0);
        #pragma unroll
        for (int j = 0; j < 4; ++j) {
            int n = wc * 64 + j * 16 + lr;
            float bj = bias[n];
            #pragma unroll
            for (int i = 0; i < MI; ++i)
                #pragma unroll
                for (int r = 0; r < 4; ++r) {
                    int m = m0 + i * 16 + lq * 4 + r;
                    acc[i][j][r] = bf2f(r16[(size_t)m * 256 + n]) + bj;
                }
        }
    } else {
        #pragma unroll
        for (int i = 0; i < MI; ++i)
            #pragma unroll
            for (int j = 0; j < 4; ++j)
                acc[i][j] = (f4v){0.f, 0.f, 0.f, 0.f};
    }

    auto stageG = [&](int s, int buf) {
        int k0 = s * 32;
        #pragma unroll
        for (int t = 0; t < AT; ++t)
            ASYNC16(gA[t] + k0, (u16*)As + buf * (BM * 32) + loA[t]);
        #pragma unroll
        for (int t = 0; t < BT; ++t)
            ASYNC16(gB[t] + k0, (u16*)Bs + buf * (BN * 32) + loB[t]);
    };
    auto computeStep = [&](int s) {
        const u16* Ab = As + (s & 1) * (BM * 32);
        const u16* Bb = Bs + (s & 1) * (BN * 32);
        bf8v af[MI], bv[4];
        #pragma unroll
        for (int i = 0; i < MI; ++i) {
            int row = wr * MROWS + i * 16 + lr;
            af[i] = *(const bf8v*)&Ab[row * 32 + ((lq ^ ((row >> 1) & 3)) << 3)];
        }
        #pragma unroll
        for (int j = 0; j < 4; ++j) {
            int row = wc * 64 + j * 16 + lr;
            bv[j] = *(const bf8v*)&Bb[row * 32 + ((lq ^ ((row >> 1) & 3)) << 3)];
        }
        #pragma unroll
        for (int i = 0; i < MI; ++i)
            #pragma unroll
            for (int j = 0; j < 4; ++j)
                acc[i][j] = __builtin_amdgcn_mfma_f32_16x16x32_bf16(af[i], bv[j], acc[i][j], 0, 0, 0);
    };

    stageG(0, 0);
    __syncthreads();
    for (int s = 0; s < NSTEPS - 1; ++s) {
        stageG(s + 1, (s + 1) & 1);
        computeStep(s);
        __syncthreads();
    }
    computeStep(NSTEPS - 1);

    // -------------------- epilogue --------------------
    if constexpr (EPI == 7 || EPI == 9) {
        float g4[4], b4[4];
        #pragma unroll
        for (int j = 0; j < 4; ++j) {
            int n = wc * 64 + j * 16 + lr;
            g4[j] = p0[n]; b4[j] = p1[n];
        }
        #pragma unroll
        for (int i = 0; i < MI; ++i)
            #pragma unroll
            for (int r = 0; r < 4; ++r) {
                float p = 0.f, p2 = 0.f;
                #pragma unroll
                for (int j = 0; j < 4; ++j) { float v = acc[i][j][r]; p += v; p2 += v * v; }
                p += __shfl_xor(p, 1, 16);  p2 += __shfl_xor(p2, 1, 16);
                p += __shfl_xor(p, 2, 16);  p2 += __shfl_xor(p2, 2, 16);
                p += __shfl_xor(p, 4, 16);  p2 += __shfl_xor(p2, 4, 16);
                p += __shfl_xor(p, 8, 16);  p2 += __shfl_xor(p2, 8, 16);
                if (lr == 0) {
                    int row = i * 16 + lq * 4 + r;
                    red[w][row][0] = p; red[w][row][1] = p2;
                }
            }
        __syncthreads();

        if constexpr (EPI == 7) {
            #pragma unroll
            for (int i = 0; i < MI; ++i) {
                float mean4[4], rstd4[4];
                #pragma unroll
                for (int r = 0; r < 4; ++r) {
                    int row = i * 16 + lq * 4 + r;
                    float s  = red[0][row][0] + red[1][row][0] + red[2][row][0] + red[3][row][0];
                    float s2 = red[0][row][1] + red[1][row][1] + red[2][row][1] + red[3][row][1];
                    float mean = s * (1.f / 256.f);
                    float var  = s2 * (1.f / 256.f) - mean * mean;
                    mean4[r] = mean;
                    rstd4[r] = rsqrtf(var + 1e-5f);
                }
                #pragma unroll
                for (int r = 0; r < 4; ++r) {
                    int m = m0 + i * 16 + lq * 4 + r;
                    int b = m >> 14, sp = m & (NNn - 1);
                    size_t pb = (((size_t)b * PADW + (sp >> 7) + 1) * PADW + (sp & 127) + 1) * 512 + choff;
                    #pragma unroll
                    for (int j = 0; j < 4; ++j) {
                        int n = wc * 64 + j * 16 + lr;
                        outb[pb + n] = f2bf((acc[i][j][r] - mean4[r]) * rstd4[r] * g4[j] + b4[j]);
                    }
                }
            }
        } else {
            // EPI 9: LDS-transposed coalesced write to (B,C,N) + cam residual.
            __shared__ float tb[4][16][68];   // per wave: [n-local][m 64 + pad]
            float mean_a[MI][4], rstd_a[MI][4];
            #pragma unroll
            for (int i = 0; i < MI; ++i)
                #pragma unroll
                for (int r = 0; r < 4; ++r) {
                    int row = i * 16 + lq * 4 + r;
                    float s  = red[0][row][0] + red[1][row][0] + red[2][row][0] + red[3][row][0];
                    float s2 = red[0][row][1] + red[1][row][1] + red[2][row][1] + red[3][row][1];
                    float mean = s * (1.f / 256.f);
                    float var  = s2 * (1.f / 256.f) - mean * mean;
                    mean_a[i][r] = mean;
                    rstd_a[i][r] = rsqrtf(var + 1e-5f);
                }
            const int bloc = m0 >> 14;
            const int spb  = m0 & (NNn - 1);
            const int nl = lane >> 2;          // 0..15
            const int ms = (lane & 3) * 16;    // 0,16,32,48
            #pragma unroll
            for (int j = 0; j < 4; ++j) {
                // stage this wave's 64(m) x 16(n) normalized tile (same-wave RAW)
                #pragma unroll
                for (int i = 0; i < MI; ++i)
                    #pragma unroll
                    for (int r = 0; r < 4; ++r)
                        tb[w][lr][i * 16 + lq * 4 + r] =
                            (acc[i][j][r] - mean_a[i][r]) * rstd_a[i][r] * g4[j] + b4[j];
                int ng = wc * 64 + j * 16 + nl;
                size_t ob = ((size_t)bloc * 256 + ng) * NNn + spb + ms;
                #pragma unroll
                for (int t = 0; t < 4; ++t) {
                    float4 cv = *(const float4*)&outf2[ob + t * 4];
                    float4 vv = *(const float4*)&tb[w][nl][ms + t * 4];
                    float4 o;
                    o.x = vv.x + cv.x; o.y = vv.y + cv.y;
                    o.z = vv.z + cv.z; o.w = vv.w + cv.w;
                    *(float4*)&outf[ob + t * 4] = o;
                }
            }
        }
        return;
    }

    float bj[4]; int ncol[4];
    #pragma unroll
    for (int j = 0; j < 4; ++j) {
        int n = n0 + wc * 64 + j * 16 + lr;
        ncol[j] = n;
        if constexpr (EPI == 4 || EPI == 5) bj[j] = bias[n];
    }
    #pragma unroll
    for (int i = 0; i < MI; ++i) {
        #pragma unroll
        for (int r = 0; r < 4; ++r) {
            int m = m0 + wr * MROWS + i * 16 + lq * 4 + r;
            size_t pb = 0;
            if constexpr (EPI == 4) {
                int b = m >> 14, sp = m & (NNn - 1);
                pb = (((size_t)b * PADW + (sp >> 7) + 1) * PADW + (sp & 127) + 1) * 512;
            }
            #pragma unroll
            for (int j = 0; j < 4; ++j) {
                int n = ncol[j];
                float v = acc[i][j][r];
                size_t oi = (size_t)m * Nc + n;
                if constexpr (EPI == 4) {
                    float vv = v + bj[j];
                    float g = 1.f / (1.f + __expf(-vv));
                    float f = g * bf2f(img[pb + n]) + (1.f - g) * bf2f(img[pb + 256 + n]);
                    outb[oi] = f2bf(f);
                } else if constexpr (EPI == 5) {
                    outb[oi] = f2bf(fmaxf(v + bj[j], 0.f));
                }
            }
        }
    }
}

// ---------------------------------------------------------------------------
// fused vp + oa projections, one launch. BM=BN=128, BK=32 dbuf, KK=256.
// ---------------------------------------------------------------------------
__global__ __launch_bounds__(256)
void vpoa_k(const u16* __restrict__ qcam, const u16* __restrict__ wvp,
            const u16* __restrict__ woa, const float* __restrict__ biasbf,
            u16* __restrict__ valb, float* __restrict__ offb,
            float* __restrict__ attwb)
{
    __shared__ __align__(16) u16 As[2 * 128 * 32];
    __shared__ __align__(16) u16 Bs[2 * 128 * 32];

    const int bx = blockIdx.x;
    int job, zs, by, n0;
    if (bx < 1024) { job = 0; zs = bx >> 9; int r = bx & 511; n0 = (r & 1) * 128; by = r >> 1; }
    else           { job = 1; int r = bx - 1024; zs = r >> 8; by = r & 255; n0 = 0; }

    const u16* A  = job == 0 ? qcam + (size_t)(1 - zs) * MTOT * CCn
                             : qcam + (size_t)zs * MTOT * CCn;
    const u16* Wt = job == 0 ? wvp + zs * 65536 : woa + zs * 32768;

    const int tid  = threadIdx.x;
    const int lane = tid & 63;
    const int w    = tid >> 6;
    const int wr   = w >> 1, wc = w & 1;
    const int m0 = by * 128;
    const int lr = lane & 15, lq = lane >> 4;

    const u16* gA[2]; int loA[2];
    const u16* gB[2]; int loB[2];
    #pragma unroll
    for (int t = 0; t < 2; ++t) {
        int c = t * 256 + tid; int row = c >> 2; int part = c & 3;
        int pg = part ^ ((row >> 1) & 3);
        gA[t] = A + (size_t)(m0 + row) * 256 + pg * 8;
        gB[t] = Wt + (size_t)(n0 + row) * 256 + pg * 8;
        loA[t] = c * 8; loB[t] = c * 8;
    }

    f4v acc[4][4];
    #pragma unroll
    for (int i = 0; i < 4; ++i)
        #pragma unroll
        for (int j = 0; j < 4; ++j)
            acc[i][j] = (f4v){0.f, 0.f, 0.f, 0.f};

    auto stageG = [&](int s, int buf) {
        int k0 = s * 32;
        #pragma unroll
        for (int t = 0; t < 2; ++t) {
            ASYNC16(gA[t] + k0, (u16*)As + buf * (128 * 32) + loA[t]);
            ASYNC16(gB[t] + k0, (u16*)Bs + buf * (128 * 32) + loB[t]);
        }
    };
    auto computeStep = [&](int s) {
        const u16* Ab = As + (s & 1) * (128 * 32);
        const u16* Bb = Bs + (s & 1) * (128 * 32);
        bf8v af[4], bv[4];
        #pragma unroll
        for (int i = 0; i < 4; ++i) {
            int row = wr * 64 + i * 16 + lr;
            af[i] = *(const bf8v*)&Ab[row * 32 + ((lq ^ ((row >> 1) & 3)) << 3)];
        }
        #pragma unroll
        for (int j = 0; j < 4; ++j) {
            int row = wc * 64 + j * 16 + lr;
            bv[j] = *(const bf8v*)&Bb[row * 32 + ((lq ^ ((row >> 1) & 3)) << 3)];
        }
        #pragma unroll
        for (int i = 0; i < 4; ++i)
            #pragma unroll
            for (int j = 0; j < 4; ++j)
                acc[i][j] = __builtin_amdgcn_mfma_f32_16x16x32_bf16(af[i], bv[j], acc[i][j], 0, 0, 0);
    };

    stageG(0, 0);
    __syncthreads();
    for (int s = 0; s < 7; ++s) {
        stageG(s + 1, (s + 1) & 1);
        computeStep(s);
        __syncthreads();
    }
    computeStep(7);

    if (job == 0) {
        u16* outb = valb + (size_t)zs * MTOT * CCn;
        const float* bias = biasbf + zs * 256;
        float bj[4]; int ncol[4];
        #pragma unroll
        for (int j = 0; j < 4; ++j) {
            int n = n0 + wc * 64 + j * 16 + lr;
            ncol[j] = n; bj[j] = bias[n];
        }
        #pragma unroll
        for (int i = 0; i < 4; ++i)
            #pragma unroll
            for (int r = 0; r < 4; ++r) {
                int m = m0 + wr * 64 + i * 16 + lq * 4 + r;
                #pragma unroll
                for (int j = 0; j < 4; ++j)
                    outb[(size_t)m * 256 + ncol[j]] = f2bf(acc[i][j][r] + bj[j]);
            }
    } else {
        float* of = offb + (size_t)zs * MTOT * 64;
        float* aw = attwb + (size_t)zs * MTOT * 32;
        const float* p0 = biasbf + 1024 + zs * 96;
        const float* p1 = biasbf + 1088 + zs * 96;
        #pragma unroll
        for (int i = 0; i < 4; ++i)
            #pragma unroll
            for (int r = 0; r < 4; ++r) {
                int m = m0 + wr * 64 + i * 16 + lq * 4 + r;
                #pragma unroll
                for (int j = 0; j < 4; ++j) {
                    int n = wc * 64 + j * 16 + lr;
                    float v = acc[i][j][r];
                    if (n < 64)      of[(size_t)m * 64 + n]        = v + p0[n];
                    else if (n < 96) aw[(size_t)m * 32 + (n - 64)] = v + p1[n - 64];
                }
            }
    }
}

// ---------------------------------------------------------------------------
// dedicated conv kernel: 128x128 tile, BK=32, double-buffered stage-ahead
// (one barrier/step), both-sides XOR swizzle chunk^=((row>>1)&3).
// split-K = 3 (3 taps per z). bf16 partial out. grid (1, 256, 3).
// ---------------------------------------------------------------------------
template<int TAPS>
__global__ __launch_bounds__(256)
void conv_k(const u16* __restrict__ img, const u16* __restrict__ Wt,
            u16* __restrict__ outp)
{
    constexpr int NS = TAPS * 16;
    __shared__ __align__(16) u16 As[2 * 128 * 32];
    __shared__ __align__(16) u16 Bs[2 * 128 * 32];

    const int z = blockIdx.z;
    outp += (size_t)z * MTOT * 128;
    const int tid = threadIdx.x;
    const int lane = tid & 63;
    const int w = tid >> 6;
    const int wr = w >> 1, wc = w & 1;
    int by = blockIdx.y;
    by = ((by & 7) << 5) | (by >> 3);       // XCD swizzle (256 = 8*32)
    const int m0 = by * 128;
    const int lr = lane & 15, lq = lane >> 4;

    // staging: 2 chunks/thread each; c = t*256+tid, row=c>>2, part=c&3
    const u16* abase[2]; const u16* bbase[2]; int ldsOff[2];
    #pragma unroll
    for (int t = 0; t < 2; ++t) {
        int c = t * 256 + tid;
        int row = c >> 2, part = c & 3;
        int pg = part ^ ((row >> 1) & 3);
        ldsOff[t] = c * 8;
        int m = m0 + row; int b = m >> 14; int sp = m & (NNn - 1);
        long cb = ((long)b * PADW + (sp >> 7)) * PADW + (sp & 127);
        abase[t] = img + cb * 512 + pg * 8;
        bbase[t] = Wt + (size_t)row * 4608 + pg * 8;
    }

    long adel[TAPS]; int bdel[TAPS];
    #pragma unroll
    for (int tt = 0; tt < TAPS; ++tt) {
        int tap = z * TAPS + tt;
        int dy = tap / 3, dx = tap - dy * 3;
        adel[tt] = (long)(dy * PADW + dx) * 512;
        bdel[tt] = tap * 512;
    }

    f4v acc[4][4];
    #pragma unroll
    for (int i = 0; i < 4; ++i)
        #pragma unroll
        for (int j = 0; j < 4; ++j)
            acc[i][j] = (f4v){0.f, 0.f, 0.f, 0.f};

    auto stage = [&](int s, int buf) {
        int tt = s >> 4;
        int ci = (s & 15) * 32;
        #pragma unroll
        for (int t = 0; t < 2; ++t) {
            ASYNC16(abase[t] + adel[tt] + ci, (u16*)As + buf * (128 * 32) + ldsOff[t]);
            ASYNC16(bbase[t] + bdel[tt] + ci, (u16*)Bs + buf * (128 * 32) + ldsOff[t]);
        }
    };
    auto computeStep = [&](int s) {
        const u16* Ab = As + (s & 1) * (128 * 32);
        const u16* Bb = Bs + (s & 1) * (128 * 32);
        bf8v af[4], bv[4];
        #pragma unroll
        for (int i = 0; i < 4; ++i) {
            int row = wr * 64 + i * 16 + lr;
            af[i] = *(const bf8v*)&Ab[row * 32 + ((lq ^ ((row >> 1) & 3)) << 3)];
        }
        #pragma unroll
        for (int j = 0; j < 4; ++j) {
            int row = wc * 64 + j * 16 + lr;
            bv[j] = *(const bf8v*)&Bb[row * 32 + ((lq ^ ((row >> 1) & 3)) << 3)];
        }
        #pragma unroll
        for (int i = 0; i < 4; ++i)
            #pragma unroll
            for (int j = 0; j < 4; ++j)
                acc[i][j] = __builtin_amdgcn_mfma_f32_16x16x32_bf16(af[i], bv[j], acc[i][j], 0, 0, 0);
    };

    stage(0, 0);
    __syncthreads();
    #pragma unroll 4
    for (int s = 0; s < NS - 1; ++s) {
        stage(s + 1, (s + 1) & 1);
        computeStep(s);
        __syncthreads();
    }
    computeStep(NS - 1);

    #pragma unroll
    for (int i = 0; i < 4; ++i)
        #pragma unroll
        for (int r = 0; r < 4; ++r) {
            int m = m0 + wr * 64 + i * 16 + lq * 4 + r;
            #pragma unroll
            for (int j = 0; j < 4; ++j) {
                int n = wc * 64 + j * 16 + lr;
                outp[(size_t)m * 128 + n] = f2bf(acc[i][j][r]);
            }
        }
}

// ---------------------------------------------------------------------------
// split-K combine (3 bf16 partials) + BN + ReLU -> bf16
// ---------------------------------------------------------------------------
__global__ __launch_bounds__(256)
void combine_k(const u16* __restrict__ part, const float* __restrict__ bng,
               const float* __restrict__ bnb, u16* __restrict__ hb)
{
    const float bnscale = rsqrtf(1.0f + 1e-5f);
    int i = (blockIdx.x * 256 + threadIdx.x) * 4;   // over MTOT*128
    int n = i & 127;
    float s0 = 0.f, s1 = 0.f, s2 = 0.f, s3 = 0.f;
    #pragma unroll
    for (int p = 0; p < 3; ++p) {
        ushort4 a = *(const ushort4*)&part[(size_t)p * MTOT * 128 + i];
        s0 += bf2f(a.x); s1 += bf2f(a.y); s2 += bf2f(a.z); s3 += bf2f(a.w);
    }
    ushort4 o;
    o.x = f2bf(fmaxf(s0 * bnscale * bng[n + 0] + bnb[n + 0], 0.f));
    o.y = f2bf(fmaxf(s1 * bnscale * bng[n + 1] + bnb[n + 1], 0.f));
    o.z = f2bf(fmaxf(s2 * bnscale * bng[n + 2] + bnb[n + 2], 0.f));
    o.w = f2bf(fmaxf(s3 * bnscale * bng[n + 3] + bnb[n + 3], 0.f));
    *(ushort4*)&hb[i] = o;
}

// ---------------------------------------------------------------------------
// fused prologue: tcvt (4096 blocks) | repack (4746 blocks) | zring (258)
// flat grid 9100 x 256 threads.
// ---------------------------------------------------------------------------
__global__ __launch_bounds__(256)
void prologue_k(const float* __restrict__ cam, const float* __restrict__ sat,
                u16* __restrict__ qcam, u16* __restrict__ qsat,
                const float* __restrict__ vp1, const float* __restrict__ op1,
                const float* __restrict__ vp2, const float* __restrict__ op2,
                const float* __restrict__ f1w, const float* __restrict__ f2w,
                const float* __restrict__ of1, const float* __restrict__ aw1,
                const float* __restrict__ of2, const float* __restrict__ aw2,
                const float* __restrict__ g1,  const float* __restrict__ g2,
                const float* __restrict__ vpb1, const float* __restrict__ vpb2,
                const float* __restrict__ opb1, const float* __restrict__ opb2,
                const float* __restrict__ ofb1, const float* __restrict__ awb1,
                const float* __restrict__ ofb2, const float* __restrict__ awb2,
                const float* __restrict__ l1g, const float* __restrict__ l1b,
                const float* __restrict__ l2g, const float* __restrict__ l2b,
                u16* __restrict__ wb, float* __restrict__ bb,
                u16* __restrict__ pad)
{
    __shared__ float t[64][65];
    const int bx = blockIdx.x;
    const int tid = threadIdx.x;

    if (bx < 4096) {
        // -------- tcvt --------
        int x = bx & 3, y = (bx >> 2) & 255, zz = bx >> 10;
        const float* src = (zz < 2) ? cam : sat;
        u16* dst = (zz < 2) ? qcam : qsat;
        int b = zz & 1;
        int c0 = x * 64, sp0 = y * 64;
        #pragma unroll
        for (int it = 0; it < 16; ++it) {
            int idx = it * 256 + tid;
            int cl = idx >> 6, sl = idx & 63;
            t[cl][sl] = src[((size_t)(b * CCn + c0 + cl)) * NNn + sp0 + sl];
        }
        __syncthreads();
        #pragma unroll
        for (int it = 0; it < 16; ++it) {
            int idx = it * 256 + tid;
            int sl = idx >> 6, cl = idx & 63;
            dst[((size_t)(b * NNn + sp0 + sl)) * CCn + c0 + cl] = f2bf(t[cl][sl]);
        }
        return;
    }
    if (bx < 8842) {
        // -------- repack --------
        int i = (bx - 4096) * 256 + tid;
        if (i >= 1212416 + 2240) return;
        if (i >= 1212416) {
            int j = i - 1212416;
            float v;
            if      (j < 256)  v = vpb1[j];
            else if (j < 512)  v = vpb2[j - 256];
            else if (j < 768)  v = opb1[j - 512];
            else if (j < 1024) v = opb2[j - 768];
            else if (j < 1088) v = ofb1[j - 1024];
            else if (j < 1120) v = awb1[j - 1088];
            else if (j < 1184) v = ofb2[j - 1120];
            else if (j < 1216) v = awb2[j - 1184];
            else if (j < 1472) v = l1g[j - 1216];
            else if (j < 1728) v = l1b[j - 1472];
            else if (j < 1984) v = l2g[j - 1728];
            else               v = l2b[j - 1984];
            bb[j] = v;
            return;
        }
        float v;
        if (i < 262144) {
            const float* src[4] = { vp1, vp2, op1, op2 };
            int q = i >> 16, j = i & 65535;
            int n = j >> 8, k = j & 255;
            v = src[q][(size_t)k * 256 + n];
        } else if (i < 393216) {
            int j = i - 262144; int n = j >> 8, k = j & 255;      // [512][256]
            v = f1w[(size_t)k * 512 + n];
        } else if (i < 524288) {
            int j = i - 393216; int n = j >> 9, k = j & 511;      // [256][512]
            v = f2w[(size_t)k * 256 + n];
        } else if (i < 589824) {
            int jj = i - 524288; int hh = jj >> 15; int j = jj & 32767;
            int n = j >> 8, k = j & 255;                          // [128][256]
            const float* ofw = hh ? of2 : of1;
            const float* aww = hh ? aw2 : aw1;
            if (n < 64)      v = ofw[(size_t)k * 64 + n];
            else if (n < 96) v = aww[(size_t)k * 32 + (n - 64)];
            else             v = 0.f;
        } else if (i < 1179648) {
            int j = i - 589824; int co = j / 4608, k = j - co * 4608;
            int tap = k >> 9, ci = k & 511;
            v = g1[((size_t)co * 512 + ci) * 9 + tap];
        } else {
            int j = i - 1179648; int n = j >> 7, k = j & 127;     // [256][128]
            v = g2[(size_t)n * 128 + k];
        }
        wb[i] = f2bf(v);
        return;
    }
    // -------- zring --------
    {
        int i = (bx - 8842) * 256 + tid;
        if (i >= 66048) return;
        int e = i * 8;
        const int per_b = 264192;
        int b = e / per_b; int r = e - b * per_b;
        long off;
        if (r < 66560)       { int x = r >> 9, c = r & 511;                 off = (((long)b * PADW + 0)   * PADW + x)   * 512 + c; }
        else if (r < 133120) { int r2 = r - 66560;  int x = r2 >> 9, c = r2 & 511; off = (((long)b * PADW + 129) * PADW + x)   * 512 + c; }
        else if (r < 198656) { int r2 = r - 133120; int y = (r2 >> 9) + 1, c = r2 & 511; off = (((long)b * PADW + y)   * PADW + 0)   * 512 + c; }
        else                 { int r2 = r - 198656; int y = (r2 >> 9) + 1, c = r2 & 511; off = (((long)b * PADW + y)   * PADW + 129) * 512 + c; }
        *(u16x8*)(pad + off) = (u16x8){0, 0, 0, 0, 0, 0, 0, 0};
    }
}

// ---------------------------------------------------------------------------
// deformable sampling, two-phase (descriptors in LDS, coalesced gathers).
// 4 lanes per (row,head), ushort8 (16B) loads. block = 64 rh; grid (4096,1,2).
// ---------------------------------------------------------------------------
__global__ __launch_bounds__(256)
void sample_k(const u16* __restrict__ val, const float* __restrict__ off,
              const float* __restrict__ lg, u16* __restrict__ outp)
{
    __shared__ uint2 desc[64][17];     // padded stride: avoid fixed-k bank camp

    int z = blockIdx.z;
    val  += (size_t)z * MTOT * CCn;
    off  += (size_t)z * MTOT * 64;
    lg   += (size_t)z * MTOT * 32;
    outp += (size_t)z * MTOT * CCn;

    const int tid = threadIdx.x;
    const int rh0 = blockIdx.x * 64;           // first row-head of block

    if (tid < 64) {
        int rhg = rh0 + tid;
        int h = rhg & 7, rn = rhg >> 3;
        int n = rn & (NNn - 1), b = rn >> 14;
        int yp = n >> 7, xp = n & 127;

        const float* ofp = off + (size_t)rn * 64 + h * 8;
        const float* lgp = lg  + (size_t)rn * 32 + h * 4;
        float4 of0 = *(const float4*)ofp;
        float4 of1 = *(const float4*)(ofp + 4);
        float4 lgv = *(const float4*)lgp;
        float ofx[4] = { of0.x, of0.z, of1.x, of1.z };
        float ofy[4] = { of0.y, of0.w, of1.y, of1.w };

        float mx = fmaxf(fmaxf(lgv.x, lgv.y), fmaxf(lgv.z, lgv.w));
        float e0 = __expf(lgv.x - mx), e1 = __expf(lgv.y - mx);
        float e2 = __expf(lgv.z - mx), e3 = __expf(lgv.w - mx);
        float inv = 1.f / (e0 + e1 + e2 + e3);
        float aw[4] = { e0 * inv, e1 * inv, e2 * inv, e3 * inv };

        unsigned hb = (unsigned)(b * NNn) * 256u + h * 32;
        #pragma unroll
        for (int p = 0; p < 4; ++p) {
            float xs = (float)xp + ofx[p];
            float ys = (float)yp + ofy[p];
            float x0f = floorf(xs), y0f = floorf(ys);
            float lx = xs - x0f, ly = ys - y0f;
            int x0 = (int)x0f, y0 = (int)y0f;
            #pragma unroll
            for (int c = 0; c < 4; ++c) {
                int xi = x0 + (c & 1), yi = y0 + (c >> 1);
                bool valid = (xi >= 0) & (xi < WWn) & (yi >= 0) & (yi < HHn);
                float wgt = valid
                    ? aw[p] * ((c & 1) ? lx : 1.f - lx) * ((c >> 1) ? ly : 1.f - ly)
                    : 0.f;
                int xc = min(max(xi, 0), WWn - 1);
                int yc = min(max(yi, 0), HHn - 1);
                unsigned addr = hb + (unsigned)(yc * WWn + xc) * 256u;
                desc[tid][p * 4 + c] = make_uint2(addr, __float_as_uint(wgt));
            }
        }
    }
    __syncthreads();

    const int rh = tid >> 2;                   // 0..63
    const int q  = tid & 3;                    // 8-channel slice
    const int rhg = rh0 + rh;
    const int h = rhg & 7, rn = rhg >> 3;

    float a[8];
    #pragma unroll
    for (int e = 0; e < 8; ++e) a[e] = 0.f;
    #pragma unroll
    for (int k = 0; k < 16; ++k) {
        uint2 d = desc[rh][k];
        float wgt = __uint_as_float(d.y);
        u16x8 v = *(const u16x8*)(val + d.x + q * 8);
        #pragma unroll
        for (int e = 0; e < 8; ++e)
            a[e] += wgt * bf2f(v[e]);
    }
    u16x8 o;
    #pragma unroll
    for (int e = 0; e < 8; ++e) o[e] = f2bf(a[e]);
    *(u16x8*)(outp + (size_t)rn * CCn + h * 32 + q * 8) = o;
}

// ---------------------------------------------------------------------------
extern "C" void kernel_launch(void* const* d_in, const int* in_sizes, int n_in,
                              void* d_out, int out_size, void* d_ws, size_t ws_size,
                              hipStream_t stream)
{
    const float* cam_bev   = (const float*)d_in[0];
    const float* sat_bev   = (const float*)d_in[1];
    const float* c2s_off_w  = (const float*)d_in[2];
    const float* c2s_off_b  = (const float*)d_in[3];
    const float* c2s_attw_w = (const float*)d_in[4];
    const float* c2s_attw_b = (const float*)d_in[5];
    const float* c2s_vp_w   = (const float*)d_in[6];
    const float* c2s_vp_b   = (const float*)d_in[7];
    const float* c2s_op_w   = (const float*)d_in[8];
    const float* c2s_op_b   = (const float*)d_in[9];
    const float* s2c_off_w  = (const float*)d_in[10];
    const float* s2c_off_b  = (const float*)d_in[11];
    const float* s2c_attw_w = (const float*)d_in[12];
    const float* s2c_attw_b = (const float*)d_in[13];
    const float* s2c_vp_w   = (const float*)d_in[14];
    const float* s2c_vp_b   = (const float*)d_in[15];
    const float* s2c_op_w   = (const float*)d_in[16];
    const float* s2c_op_b   = (const float*)d_in[17];
    const float* ln1_g = (const float*)d_in[18];
    const float* ln1_b = (const float*)d_in[19];
    const float* ln2_g = (const float*)d_in[20];
    const float* ln2_b = (const float*)d_in[21];
    const float* lnf_g = (const float*)d_in[22];
    const float* lnf_b = (const float*)d_in[23];
    const float* ffn1_w = (const float*)d_in[24];
    const float* ffn1_b = (const float*)d_in[25];
    const float* ffn2_w = (const float*)d_in[26];
    const float* ffn2_b = (const float*)d_in[27];
    const float* g1_w  = (const float*)d_in[28];
    const float* bn_g  = (const float*)d_in[29];
    const float* bn_b  = (const float*)d_in[30];
    const float* g2_w  = (const float*)d_in[31];
    const float* g2_b  = (const float*)d_in[32];

    char* base = (char*)d_ws;
    size_t off = 0;
    auto alloc = [&](size_t bytes) -> void* {
        void* p = base + off;
        off += (bytes + 255) & ~(size_t)255;
        return p;
    };

    u16*   qcam   = (u16*)  alloc((size_t)MTOT * CCn * 2 * 2);   // qcam|qsat contiguous
    u16*   qsat   = qcam + (size_t)MTOT * CCn;
    u16*   valb   = (u16*)  alloc((size_t)MTOT * CCn * 2 * 2);   // pair
    u16*   sampb  = (u16*)  alloc((size_t)MTOT * CCn * 2 * 2);   // pair (33.55MB)
    float* offb   = (float*)alloc((size_t)MTOT * 64 * 4 * 2);    // pair (16.78MB)
    float* attwb  = (float*)alloc((size_t)MTOT * 32 * 4 * 2);    // pair
    size_t padBytes = (size_t)BBn * PADW * PADW * 512 * 2;       // 34.6MB
    u16*   pad    = (u16*)  alloc(padBytes);
    u16*   hbuf   = (u16*)  alloc((size_t)MTOT * 128 * 2);
    u16*   convpart = (u16*)alloc((size_t)3 * MTOT * 128 * 2);   // 25.2MB
    u16*   wbase  = (u16*)  alloc((size_t)1212416 * 2);
    float* biasbf = (float*)alloc((size_t)2240 * 4);
    // weight slices
    u16* wvp = wbase;                 // pair, stride 65536
    u16* wop = wbase + 131072;        // pair, stride 65536
    u16* wf1 = wbase + 262144;
    u16* wf2 = wbase + 393216;
    u16* woa = wbase + 524288;        // pair, stride 32768
    u16* wcv = wbase + 589824;
    u16* wg2 = wbase + 1179648;
    // aliases (temporally disjoint)
    u16*   fused_bf = valb;              // valb dead after sampling
    u16*   midb     = qcam;              // qcam/qsat dead after op-pair (MTOT*512 bf16)

    dim3 blk(256);
    ZOff zz{0, 0, 0, 0, 0, 0, 0, 0, 0};

    // ---------- fused prologue: tcvt | repack | zring ----------
    prologue_k<<<9100, blk, 0, stream>>>(
        cam_bev, sat_bev, qcam, qsat,
        c2s_vp_w, c2s_op_w, s2c_vp_w, s2c_op_w,
        ffn1_w, ffn2_w, c2s_off_w, c2s_attw_w,
        s2c_off_w, s2c_attw_w, g1_w, g2_w,
        c2s_vp_b, s2c_vp_b, c2s_op_b, s2c_op_b,
        c2s_off_b, c2s_attw_b, s2c_off_b, s2c_attw_b,
        ln1_g, ln1_b, ln2_g, ln2_b,
        wbase, biasbf, pad);

    // ---------- fused value + offset/attw projections ----------
    vpoa_k<<<1536, blk, 0, stream>>>(qcam, wvp, woa, biasbf, valb, offb, attwb);

    // ---------- deformable sampling (both streams, 2-phase, 16B gathers) ----
    sample_k<<<dim3(4096, 1, 2), blk, 0, stream>>>(valb, offb, attwb, sampb);
    // ---------- output projections + residual + LN -> pad image ----------
    {
        ZOff zo{ (long)MTOT * CCn, 65536, 256, 0, 0, 0, (long)MTOT * CCn, 512, 256 };
        mgemm<64, 256, 4, 7, 256><<<dim3(1, 512, 2), blk, 0, stream>>>(
            sampb, wop, biasbf + 512, 256, 256,
            nullptr, nullptr, pad, nullptr, qcam, biasbf + 1216, biasbf + 1472, 0, zo);
    }
    // ---------- gating conv: BK=32 dbuf, split-K=3, bf16 partials ----------
    conv_k<3><<<dim3(1, 256, 3), blk, 0, stream>>>(pad, wcv, convpart);
    combine_k<<<4096, blk, 0, stream>>>(convpart, bn_g, bn_b, hbuf);

    // ---------- 1x1 conv + sigmoid + gated fusion (bf16 out, BM=64) ----------
    mgemm<64, 128, 2, 4, 128><<<dim3(2, 512, 1), blk, 0, stream>>>(
        hbuf, wg2, g2_b, 128, 256,
        nullptr, nullptr, fused_bf, pad, nullptr, nullptr, nullptr, 0, zz);

    // ---------- FFN ----------
    mgemm<128, 128, 2, 5, 256><<<dim3(4, 256, 1), blk, 0, stream>>>(
        fused_bf, wf1, ffn1_b, 256, 512,
        nullptr, nullptr, midb, nullptr, nullptr, nullptr, nullptr, 0, zz);
    // ffn2 + final LN + coalesced transposed write to (B,C,N) + cam residual
    mgemm<64, 256, 4, 9, 512><<<dim3(1, 512, 1), blk, 0, stream>>>(
        midb, wf2, ffn2_b, 512, 256,
        (float*)d_out, (float*)cam_bev, nullptr, nullptr, fused_bf, lnf_g, lnf_b, 0, zz);
}

// Round 21
// 269.555 us; speedup vs baseline: 1.0517x; 1.0517x over previous
//
#include <hip/hip_runtime.h>
#include <hip/hip_bf16.h>
#include <cstddef>

#define BBn  2
#define CCn  256
#define HHn  128
#define WWn  128
#define NNn  (HHn*WWn)        // 16384
#define MTOT (BBn*NNn)        // 32768
#define PADW 130

typedef unsigned short u16;
typedef __attribute__((ext_vector_type(8))) short bf8v;
typedef __attribute__((ext_vector_type(8))) unsigned short u16x8;
typedef __attribute__((ext_vector_type(4))) float f4v;

typedef __attribute__((address_space(1))) const void gvoid_t;
typedef __attribute__((address_space(3))) void svoid_t;
#define ASYNC16(g, l) __builtin_amdgcn_global_load_lds((gvoid_t*)(g), (svoid_t*)(l), 16, 0, 0)

__device__ __forceinline__ u16 f2bf(float f) {
    __hip_bfloat16 h = __float2bfloat16(f);
    return *reinterpret_cast<u16*>(&h);
}
__device__ __forceinline__ float bf2f(u16 h) {
    return __uint_as_float(((unsigned)h) << 16);
}

// z-offsets (elements), applied scaled by blockIdx.z
struct ZOff {
    long a, w, bia, f1, f2, b1, r, p;
    int ch;
};

// ---------------------------------------------------------------------------
// bf16 MFMA GEMM, tile BM x BN, BK=32, double-buffered LDS (stage-ahead),
// both-sides XOR swizzle: chunk' = chunk ^ ((row>>1)&3).
// EPI: 4 sigmoid-gate (bf16 out) | 5 ReLU->bf16
//      7 resid(bf16)-init + rowLN -> pad bf16 | 9 resid(bf16)-init + rowLN -> (B,C,N) + cam
// ---------------------------------------------------------------------------
template<int BM, int BN, int WC, int EPI, int KK>
__global__ __launch_bounds__(256)
void mgemm(const u16* __restrict__ A, const u16* __restrict__ Wt,
           const float* __restrict__ bias, int ldw, int Nc,
           float* __restrict__ outf, float* __restrict__ outf2,
           u16* __restrict__ outb, const u16* __restrict__ img,
           const void* __restrict__ resid,
           const float* __restrict__ p0, const float* __restrict__ p1,
           int choff, ZOff zo)
{
    constexpr int WR = 4 / WC;
    constexpr int MROWS = BM / WR;       // rows per wave
    constexpr int MI = MROWS / 16;
    constexpr int AT = BM / 64;          // A staging chunks per thread
    constexpr int BT = BN / 64;
    constexpr int NSTEPS = KK / 32;

    __shared__ __align__(16) u16 As[2 * BM * 32];
    __shared__ __align__(16) u16 Bs[2 * BN * 32];
    __shared__ float red[4][64][2];      // LN cross-wave partials (EPI 7/9)

    const int z = blockIdx.z;
    if (z) {
        A += (long)z * zo.a; Wt += (long)z * zo.w;
        if (bias)  bias  += (long)z * zo.bia;
        if (outf)  outf  += (long)z * zo.f1;
        if (outf2) outf2 += (long)z * zo.f2;
        if (outb)  outb  += (long)z * zo.b1;
        if (p0)    p0    += (long)z * zo.p;
        if (p1)    p1    += (long)z * zo.p;
        choff += z * zo.ch;
    }

    const int tid  = threadIdx.x;
    const int lane = tid & 63;
    const int w    = tid >> 6;
    const int wr   = w / WC, wc = w % WC;
    const int by = blockIdx.y;
    const int m0 = by * BM;
    const int n0 = blockIdx.x * BN;
    const int lr = lane & 15, lq = lane >> 4;

    // staging source pointers (source chunk pre-swizzled; LDS dest linear)
    const u16* gA[AT]; int loA[AT];
    #pragma unroll
    for (int t = 0; t < AT; ++t) {
        int c = t * 256 + tid; int row = c >> 2; int part = c & 3;
        int pg = part ^ ((row >> 1) & 3);
        gA[t] = A + (size_t)(m0 + row) * KK + pg * 8;
        loA[t] = c * 8;
    }
    const u16* gB[BT]; int loB[BT];
    #pragma unroll
    for (int t = 0; t < BT; ++t) {
        int c = t * 256 + tid; int row = c >> 2; int part = c & 3;
        int pg = part ^ ((row >> 1) & 3);
        gB[t] = Wt + (size_t)(n0 + row) * ldw + pg * 8;
        loB[t] = c * 8;
    }

    // accumulator (residual+bias init for LN epilogues; WR==1 there)
    f4v acc[MI][4];
    if constexpr (EPI == 7 || EPI == 9) {
        const u16* r16 = (const u16*)resid + (EPI == 7 ? (long)z * zo.r : 0);
        #pragma unroll
        for (int j = 0; j < 4; ++j) {
            int n = wc * 64 + j * 16 + lr;
            float bj = bias[n];
            #pragma unroll
            for (int i = 0; i < MI; ++i)
                #pragma unroll
                for (int r = 0; r < 4; ++r) {
                    int m = m0 + i * 16 + lq * 4 + r;
                    acc[i][j][r] = bf2f(r16[(size_t)m * 256 + n]) + bj;
                }
        }
    } else {
        #pragma unroll
        for (int i = 0; i < MI; ++i)
            #pragma unroll
            for (int j = 0; j < 4; ++j)
                acc[i][j] = (f4v){0.f, 0.f, 0.f, 0.f};
    }

    auto stageG = [&](int s, int buf) {
        int k0 = s * 32;
        #pragma unroll
        for (int t = 0; t < AT; ++t)
            ASYNC16(gA[t] + k0, (u16*)As + buf * (BM * 32) + loA[t]);
        #pragma unroll
        for (int t = 0; t < BT; ++t)
            ASYNC16(gB[t] + k0, (u16*)Bs + buf * (BN * 32) + loB[t]);
    };
    auto computeStep = [&](int s) {
        const u16* Ab = As + (s & 1) * (BM * 32);
        const u16* Bb = Bs + (s & 1) * (BN * 32);
        bf8v af[MI], bv[4];
        #pragma unroll
        for (int i = 0; i < MI; ++i) {
            int row = wr * MROWS + i * 16 + lr;
            af[i] = *(const bf8v*)&Ab[row * 32 + ((lq ^ ((row >> 1) & 3)) << 3)];
        }
        #pragma unroll
        for (int j = 0; j < 4; ++j) {
            int row = wc * 64 + j * 16 + lr;
            bv[j] = *(const bf8v*)&Bb[row * 32 + ((lq ^ ((row >> 1) & 3)) << 3)];
        }
        #pragma unroll
        for (int i = 0; i < MI; ++i)
            #pragma unroll
            for (int j = 0; j < 4; ++j)
                acc[i][j] = __builtin_amdgcn_mfma_f32_16x16x32_bf16(af[i], bv[j], acc[i][j], 0, 0, 0);
    };

    stageG(0, 0);
    __syncthreads();
    for (int s = 0; s < NSTEPS - 1; ++s) {
        stageG(s + 1, (s + 1) & 1);
        computeStep(s);
        __syncthreads();
    }
    computeStep(NSTEPS - 1);

    // -------------------- epilogue --------------------
    if constexpr (EPI == 7 || EPI == 9) {
        float g4[4], b4[4];
        #pragma unroll
        for (int j = 0; j < 4; ++j) {
            int n = wc * 64 + j * 16 + lr;
            g4[j] = p0[n]; b4[j] = p1[n];
        }
        #pragma unroll
        for (int i = 0; i < MI; ++i)
            #pragma unroll
            for (int r = 0; r < 4; ++r) {
                float p = 0.f, p2 = 0.f;
                #pragma unroll
                for (int j = 0; j < 4; ++j) { float v = acc[i][j][r]; p += v; p2 += v * v; }
                p += __shfl_xor(p, 1, 16);  p2 += __shfl_xor(p2, 1, 16);
                p += __shfl_xor(p, 2, 16);  p2 += __shfl_xor(p2, 2, 16);
                p += __shfl_xor(p, 4, 16);  p2 += __shfl_xor(p2, 4, 16);
                p += __shfl_xor(p, 8, 16);  p2 += __shfl_xor(p2, 8, 16);
                if (lr == 0) {
                    int row = i * 16 + lq * 4 + r;
                    red[w][row][0] = p; red[w][row][1] = p2;
                }
            }
        __syncthreads();
        #pragma unroll
        for (int i = 0; i < MI; ++i) {
            float mean4[4], rstd4[4];
            #pragma unroll
            for (int r = 0; r < 4; ++r) {
                int row = i * 16 + lq * 4 + r;
                float s  = red[0][row][0] + red[1][row][0] + red[2][row][0] + red[3][row][0];
                float s2 = red[0][row][1] + red[1][row][1] + red[2][row][1] + red[3][row][1];
                float mean = s * (1.f / 256.f);
                float var  = s2 * (1.f / 256.f) - mean * mean;
                mean4[r] = mean;
                rstd4[r] = rsqrtf(var + 1e-5f);
            }
            if constexpr (EPI == 7) {
                #pragma unroll
                for (int r = 0; r < 4; ++r) {
                    int m = m0 + i * 16 + lq * 4 + r;
                    int b = m >> 14, sp = m & (NNn - 1);
                    size_t pb = (((size_t)b * PADW + (sp >> 7) + 1) * PADW + (sp & 127) + 1) * 512 + choff;
                    #pragma unroll
                    for (int j = 0; j < 4; ++j) {
                        int n = wc * 64 + j * 16 + lr;
                        outb[pb + n] = f2bf((acc[i][j][r] - mean4[r]) * rstd4[r] * g4[j] + b4[j]);
                    }
                }
            } else {
                // transposed write to (B,C,N) + cam residual (outf2 = cam_bev)
                int mb = m0 + i * 16 + lq * 4;
                int b = mb >> 14, sp = mb & (NNn - 1);
                #pragma unroll
                for (int j = 0; j < 4; ++j) {
                    int n = wc * 64 + j * 16 + lr;
                    size_t oi = ((size_t)b * 256 + n) * NNn + sp;
                    float4 cv = *(const float4*)&outf2[oi];
                    float4 o;
                    o.x = (acc[i][j][0] - mean4[0]) * rstd4[0] * g4[j] + b4[j] + cv.x;
                    o.y = (acc[i][j][1] - mean4[1]) * rstd4[1] * g4[j] + b4[j] + cv.y;
                    o.z = (acc[i][j][2] - mean4[2]) * rstd4[2] * g4[j] + b4[j] + cv.z;
                    o.w = (acc[i][j][3] - mean4[3]) * rstd4[3] * g4[j] + b4[j] + cv.w;
                    *(float4*)&outf[oi] = o;
                }
            }
        }
        return;
    }

    float bj[4]; int ncol[4];
    #pragma unroll
    for (int j = 0; j < 4; ++j) {
        int n = n0 + wc * 64 + j * 16 + lr;
        ncol[j] = n;
        if constexpr (EPI == 4 || EPI == 5) bj[j] = bias[n];
    }
    #pragma unroll
    for (int i = 0; i < MI; ++i) {
        #pragma unroll
        for (int r = 0; r < 4; ++r) {
            int m = m0 + wr * MROWS + i * 16 + lq * 4 + r;
            size_t pb = 0;
            if constexpr (EPI == 4) {
                int b = m >> 14, sp = m & (NNn - 1);
                pb = (((size_t)b * PADW + (sp >> 7) + 1) * PADW + (sp & 127) + 1) * 512;
            }
            #pragma unroll
            for (int j = 0; j < 4; ++j) {
                int n = ncol[j];
                float v = acc[i][j][r];
                size_t oi = (size_t)m * Nc + n;
                if constexpr (EPI == 4) {
                    float vv = v + bj[j];
                    float g = 1.f / (1.f + __expf(-vv));
                    float f = g * bf2f(img[pb + n]) + (1.f - g) * bf2f(img[pb + 256 + n]);
                    outb[oi] = f2bf(f);
                } else if constexpr (EPI == 5) {
                    outb[oi] = f2bf(fmaxf(v + bj[j], 0.f));
                }
            }
        }
    }
}

// ---------------------------------------------------------------------------
// fused vp + oa projections, one launch. BM=BN=128, BK=32 dbuf, KK=256.
// ---------------------------------------------------------------------------
__global__ __launch_bounds__(256)
void vpoa_k(const u16* __restrict__ qcam, const u16* __restrict__ wvp,
            const u16* __restrict__ woa, const float* __restrict__ biasbf,
            u16* __restrict__ valb, float* __restrict__ offb,
            float* __restrict__ attwb)
{
    __shared__ __align__(16) u16 As[2 * 128 * 32];
    __shared__ __align__(16) u16 Bs[2 * 128 * 32];

    const int bx = blockIdx.x;
    int job, zs, by, n0;
    if (bx < 1024) { job = 0; zs = bx >> 9; int r = bx & 511; n0 = (r & 1) * 128; by = r >> 1; }
    else           { job = 1; int r = bx - 1024; zs = r >> 8; by = r & 255; n0 = 0; }

    const u16* A  = job == 0 ? qcam + (size_t)(1 - zs) * MTOT * CCn
                             : qcam + (size_t)zs * MTOT * CCn;
    const u16* Wt = job == 0 ? wvp + zs * 65536 : woa + zs * 32768;

    const int tid  = threadIdx.x;
    const int lane = tid & 63;
    const int w    = tid >> 6;
    const int wr   = w >> 1, wc = w & 1;
    const int m0 = by * 128;
    const int lr = lane & 15, lq = lane >> 4;

    const u16* gA[2]; int loA[2];
    const u16* gB[2]; int loB[2];
    #pragma unroll
    for (int t = 0; t < 2; ++t) {
        int c = t * 256 + tid; int row = c >> 2; int part = c & 3;
        int pg = part ^ ((row >> 1) & 3);
        gA[t] = A + (size_t)(m0 + row) * 256 + pg * 8;
        gB[t] = Wt + (size_t)(n0 + row) * 256 + pg * 8;
        loA[t] = c * 8; loB[t] = c * 8;
    }

    f4v acc[4][4];
    #pragma unroll
    for (int i = 0; i < 4; ++i)
        #pragma unroll
        for (int j = 0; j < 4; ++j)
            acc[i][j] = (f4v){0.f, 0.f, 0.f, 0.f};

    auto stageG = [&](int s, int buf) {
        int k0 = s * 32;
        #pragma unroll
        for (int t = 0; t < 2; ++t) {
            ASYNC16(gA[t] + k0, (u16*)As + buf * (128 * 32) + loA[t]);
            ASYNC16(gB[t] + k0, (u16*)Bs + buf * (128 * 32) + loB[t]);
        }
    };
    auto computeStep = [&](int s) {
        const u16* Ab = As + (s & 1) * (128 * 32);
        const u16* Bb = Bs + (s & 1) * (128 * 32);
        bf8v af[4], bv[4];
        #pragma unroll
        for (int i = 0; i < 4; ++i) {
            int row = wr * 64 + i * 16 + lr;
            af[i] = *(const bf8v*)&Ab[row * 32 + ((lq ^ ((row >> 1) & 3)) << 3)];
        }
        #pragma unroll
        for (int j = 0; j < 4; ++j) {
            int row = wc * 64 + j * 16 + lr;
            bv[j] = *(const bf8v*)&Bb[row * 32 + ((lq ^ ((row >> 1) & 3)) << 3)];
        }
        #pragma unroll
        for (int i = 0; i < 4; ++i)
            #pragma unroll
            for (int j = 0; j < 4; ++j)
                acc[i][j] = __builtin_amdgcn_mfma_f32_16x16x32_bf16(af[i], bv[j], acc[i][j], 0, 0, 0);
    };

    stageG(0, 0);
    __syncthreads();
    for (int s = 0; s < 7; ++s) {
        stageG(s + 1, (s + 1) & 1);
        computeStep(s);
        __syncthreads();
    }
    computeStep(7);

    if (job == 0) {
        u16* outb = valb + (size_t)zs * MTOT * CCn;
        const float* bias = biasbf + zs * 256;
        float bj[4]; int ncol[4];
        #pragma unroll
        for (int j = 0; j < 4; ++j) {
            int n = n0 + wc * 64 + j * 16 + lr;
            ncol[j] = n; bj[j] = bias[n];
        }
        #pragma unroll
        for (int i = 0; i < 4; ++i)
            #pragma unroll
            for (int r = 0; r < 4; ++r) {
                int m = m0 + wr * 64 + i * 16 + lq * 4 + r;
                #pragma unroll
                for (int j = 0; j < 4; ++j)
                    outb[(size_t)m * 256 + ncol[j]] = f2bf(acc[i][j][r] + bj[j]);
            }
    } else {
        float* of = offb + (size_t)zs * MTOT * 64;
        float* aw = attwb + (size_t)zs * MTOT * 32;
        const float* p0 = biasbf + 1024 + zs * 96;
        const float* p1 = biasbf + 1088 + zs * 96;
        #pragma unroll
        for (int i = 0; i < 4; ++i)
            #pragma unroll
            for (int r = 0; r < 4; ++r) {
                int m = m0 + wr * 64 + i * 16 + lq * 4 + r;
                #pragma unroll
                for (int j = 0; j < 4; ++j) {
                    int n = wc * 64 + j * 16 + lr;
                    float v = acc[i][j][r];
                    if (n < 64)      of[(size_t)m * 64 + n]        = v + p0[n];
                    else if (n < 96) aw[(size_t)m * 32 + (n - 64)] = v + p1[n - 64];
                }
            }
    }
}

// ---------------------------------------------------------------------------
// dedicated conv kernel: 128x128 tile, BK=32, double-buffered stage-ahead
// (one barrier/step), both-sides XOR swizzle chunk^=((row>>1)&3).
// split-K = 3 (3 taps per z). bf16 partial out. grid (1, 256, 3).
// ---------------------------------------------------------------------------
template<int TAPS>
__global__ __launch_bounds__(256)
void conv_k(const u16* __restrict__ img, const u16* __restrict__ Wt,
            u16* __restrict__ outp)
{
    constexpr int NS = TAPS * 16;
    __shared__ __align__(16) u16 As[2 * 128 * 32];
    __shared__ __align__(16) u16 Bs[2 * 128 * 32];

    const int z = blockIdx.z;
    outp += (size_t)z * MTOT * 128;
    const int tid = threadIdx.x;
    const int lane = tid & 63;
    const int w = tid >> 6;
    const int wr = w >> 1, wc = w & 1;
    int by = blockIdx.y;
    by = ((by & 7) << 5) | (by >> 3);       // XCD swizzle (256 = 8*32)
    const int m0 = by * 128;
    const int lr = lane & 15, lq = lane >> 4;

    // staging: 2 chunks/thread each; c = t*256+tid, row=c>>2, part=c&3
    const u16* abase[2]; const u16* bbase[2]; int ldsOff[2];
    #pragma unroll
    for (int t = 0; t < 2; ++t) {
        int c = t * 256 + tid;
        int row = c >> 2, part = c & 3;
        int pg = part ^ ((row >> 1) & 3);
        ldsOff[t] = c * 8;
        int m = m0 + row; int b = m >> 14; int sp = m & (NNn - 1);
        long cb = ((long)b * PADW + (sp >> 7)) * PADW + (sp & 127);
        abase[t] = img + cb * 512 + pg * 8;
        bbase[t] = Wt + (size_t)row * 4608 + pg * 8;
    }

    long adel[TAPS]; int bdel[TAPS];
    #pragma unroll
    for (int tt = 0; tt < TAPS; ++tt) {
        int tap = z * TAPS + tt;
        int dy = tap / 3, dx = tap - dy * 3;
        adel[tt] = (long)(dy * PADW + dx) * 512;
        bdel[tt] = tap * 512;
    }

    f4v acc[4][4];
    #pragma unroll
    for (int i = 0; i < 4; ++i)
        #pragma unroll
        for (int j = 0; j < 4; ++j)
            acc[i][j] = (f4v){0.f, 0.f, 0.f, 0.f};

    auto stage = [&](int s, int buf) {
        int tt = s >> 4;
        int ci = (s & 15) * 32;
        #pragma unroll
        for (int t = 0; t < 2; ++t) {
            ASYNC16(abase[t] + adel[tt] + ci, (u16*)As + buf * (128 * 32) + ldsOff[t]);
            ASYNC16(bbase[t] + bdel[tt] + ci, (u16*)Bs + buf * (128 * 32) + ldsOff[t]);
        }
    };
    auto computeStep = [&](int s) {
        const u16* Ab = As + (s & 1) * (128 * 32);
        const u16* Bb = Bs + (s & 1) * (128 * 32);
        bf8v af[4], bv[4];
        #pragma unroll
        for (int i = 0; i < 4; ++i) {
            int row = wr * 64 + i * 16 + lr;
            af[i] = *(const bf8v*)&Ab[row * 32 + ((lq ^ ((row >> 1) & 3)) << 3)];
        }
        #pragma unroll
        for (int j = 0; j < 4; ++j) {
            int row = wc * 64 + j * 16 + lr;
            bv[j] = *(const bf8v*)&Bb[row * 32 + ((lq ^ ((row >> 1) & 3)) << 3)];
        }
        #pragma unroll
        for (int i = 0; i < 4; ++i)
            #pragma unroll
            for (int j = 0; j < 4; ++j)
                acc[i][j] = __builtin_amdgcn_mfma_f32_16x16x32_bf16(af[i], bv[j], acc[i][j], 0, 0, 0);
    };

    stage(0, 0);
    __syncthreads();
    #pragma unroll 4
    for (int s = 0; s < NS - 1; ++s) {
        stage(s + 1, (s + 1) & 1);
        computeStep(s);
        __syncthreads();
    }
    computeStep(NS - 1);

    #pragma unroll
    for (int i = 0; i < 4; ++i)
        #pragma unroll
        for (int r = 0; r < 4; ++r) {
            int m = m0 + wr * 64 + i * 16 + lq * 4 + r;
            #pragma unroll
            for (int j = 0; j < 4; ++j) {
                int n = wc * 64 + j * 16 + lr;
                outp[(size_t)m * 128 + n] = f2bf(acc[i][j][r]);
            }
        }
}

// ---------------------------------------------------------------------------
// split-K combine (3 bf16 partials) + BN + ReLU -> bf16
// ---------------------------------------------------------------------------
__global__ __launch_bounds__(256)
void combine_k(const u16* __restrict__ part, const float* __restrict__ bng,
               const float* __restrict__ bnb, u16* __restrict__ hb)
{
    const float bnscale = rsqrtf(1.0f + 1e-5f);
    int i = (blockIdx.x * 256 + threadIdx.x) * 4;   // over MTOT*128
    int n = i & 127;
    float s0 = 0.f, s1 = 0.f, s2 = 0.f, s3 = 0.f;
    #pragma unroll
    for (int p = 0; p < 3; ++p) {
        ushort4 a = *(const ushort4*)&part[(size_t)p * MTOT * 128 + i];
        s0 += bf2f(a.x); s1 += bf2f(a.y); s2 += bf2f(a.z); s3 += bf2f(a.w);
    }
    ushort4 o;
    o.x = f2bf(fmaxf(s0 * bnscale * bng[n + 0] + bnb[n + 0], 0.f));
    o.y = f2bf(fmaxf(s1 * bnscale * bng[n + 1] + bnb[n + 1], 0.f));
    o.z = f2bf(fmaxf(s2 * bnscale * bng[n + 2] + bnb[n + 2], 0.f));
    o.w = f2bf(fmaxf(s3 * bnscale * bng[n + 3] + bnb[n + 3], 0.f));
    *(ushort4*)&hb[i] = o;
}

// ---------------------------------------------------------------------------
// fused prologue: tcvt (4096 blocks) | repack (4746 blocks) | zring (258)
// flat grid 9100 x 256 threads.
// ---------------------------------------------------------------------------
__global__ __launch_bounds__(256)
void prologue_k(const float* __restrict__ cam, const float* __restrict__ sat,
                u16* __restrict__ qcam, u16* __restrict__ qsat,
                const float* __restrict__ vp1, const float* __restrict__ op1,
                const float* __restrict__ vp2, const float* __restrict__ op2,
                const float* __restrict__ f1w, const float* __restrict__ f2w,
                const float* __restrict__ of1, const float* __restrict__ aw1,
                const float* __restrict__ of2, const float* __restrict__ aw2,
                const float* __restrict__ g1,  const float* __restrict__ g2,
                const float* __restrict__ vpb1, const float* __restrict__ vpb2,
                const float* __restrict__ opb1, const float* __restrict__ opb2,
                const float* __restrict__ ofb1, const float* __restrict__ awb1,
                const float* __restrict__ ofb2, const float* __restrict__ awb2,
                const float* __restrict__ l1g, const float* __restrict__ l1b,
                const float* __restrict__ l2g, const float* __restrict__ l2b,
                u16* __restrict__ wb, float* __restrict__ bb,
                u16* __restrict__ pad)
{
    __shared__ float t[64][65];
    const int bx = blockIdx.x;
    const int tid = threadIdx.x;

    if (bx < 4096) {
        // -------- tcvt --------
        int x = bx & 3, y = (bx >> 2) & 255, zz = bx >> 10;
        const float* src = (zz < 2) ? cam : sat;
        u16* dst = (zz < 2) ? qcam : qsat;
        int b = zz & 1;
        int c0 = x * 64, sp0 = y * 64;
        #pragma unroll
        for (int it = 0; it < 16; ++it) {
            int idx = it * 256 + tid;
            int cl = idx >> 6, sl = idx & 63;
            t[cl][sl] = src[((size_t)(b * CCn + c0 + cl)) * NNn + sp0 + sl];
        }
        __syncthreads();
        #pragma unroll
        for (int it = 0; it < 16; ++it) {
            int idx = it * 256 + tid;
            int sl = idx >> 6, cl = idx & 63;
            dst[((size_t)(b * NNn + sp0 + sl)) * CCn + c0 + cl] = f2bf(t[cl][sl]);
        }
        return;
    }
    if (bx < 8842) {
        // -------- repack --------
        int i = (bx - 4096) * 256 + tid;
        if (i >= 1212416 + 2240) return;
        if (i >= 1212416) {
            int j = i - 1212416;
            float v;
            if      (j < 256)  v = vpb1[j];
            else if (j < 512)  v = vpb2[j - 256];
            else if (j < 768)  v = opb1[j - 512];
            else if (j < 1024) v = opb2[j - 768];
            else if (j < 1088) v = ofb1[j - 1024];
            else if (j < 1120) v = awb1[j - 1088];
            else if (j < 1184) v = ofb2[j - 1120];
            else if (j < 1216) v = awb2[j - 1184];
            else if (j < 1472) v = l1g[j - 1216];
            else if (j < 1728) v = l1b[j - 1472];
            else if (j < 1984) v = l2g[j - 1728];
            else               v = l2b[j - 1984];
            bb[j] = v;
            return;
        }
        float v;
        if (i < 262144) {
            const float* src[4] = { vp1, vp2, op1, op2 };
            int q = i >> 16, j = i & 65535;
            int n = j >> 8, k = j & 255;
            v = src[q][(size_t)k * 256 + n];
        } else if (i < 393216) {
            int j = i - 262144; int n = j >> 8, k = j & 255;      // [512][256]
            v = f1w[(size_t)k * 512 + n];
        } else if (i < 524288) {
            int j = i - 393216; int n = j >> 9, k = j & 511;      // [256][512]
            v = f2w[(size_t)k * 256 + n];
        } else if (i < 589824) {
            int jj = i - 524288; int hh = jj >> 15; int j = jj & 32767;
            int n = j >> 8, k = j & 255;                          // [128][256]
            const float* ofw = hh ? of2 : of1;
            const float* aww = hh ? aw2 : aw1;
            if (n < 64)      v = ofw[(size_t)k * 64 + n];
            else if (n < 96) v = aww[(size_t)k * 32 + (n - 64)];
            else             v = 0.f;
        } else if (i < 1179648) {
            int j = i - 589824; int co = j / 4608, k = j - co * 4608;
            int tap = k >> 9, ci = k & 511;
            v = g1[((size_t)co * 512 + ci) * 9 + tap];
        } else {
            int j = i - 1179648; int n = j >> 7, k = j & 127;     // [256][128]
            v = g2[(size_t)n * 128 + k];
        }
        wb[i] = f2bf(v);
        return;
    }
    // -------- zring --------
    {
        int i = (bx - 8842) * 256 + tid;
        if (i >= 66048) return;
        int e = i * 8;
        const int per_b = 264192;
        int b = e / per_b; int r = e - b * per_b;
        long off;
        if (r < 66560)       { int x = r >> 9, c = r & 511;                 off = (((long)b * PADW + 0)   * PADW + x)   * 512 + c; }
        else if (r < 133120) { int r2 = r - 66560;  int x = r2 >> 9, c = r2 & 511; off = (((long)b * PADW + 129) * PADW + x)   * 512 + c; }
        else if (r < 198656) { int r2 = r - 133120; int y = (r2 >> 9) + 1, c = r2 & 511; off = (((long)b * PADW + y)   * PADW + 0)   * 512 + c; }
        else                 { int r2 = r - 198656; int y = (r2 >> 9) + 1, c = r2 & 511; off = (((long)b * PADW + y)   * PADW + 129) * 512 + c; }
        *(u16x8*)(pad + off) = (u16x8){0, 0, 0, 0, 0, 0, 0, 0};
    }
}

// ---------------------------------------------------------------------------
// deformable sampling, two-phase (descriptors in LDS, coalesced gathers).
// 4 lanes per (row,head), ushort8 (16B) loads. block = 64 rh; grid (4096,1,2).
// ---------------------------------------------------------------------------
__global__ __launch_bounds__(256)
void sample_k(const u16* __restrict__ val, const float* __restrict__ off,
              const float* __restrict__ lg, u16* __restrict__ outp)
{
    __shared__ uint2 desc[64][17];     // padded stride: avoid fixed-k bank camp

    int z = blockIdx.z;
    val  += (size_t)z * MTOT * CCn;
    off  += (size_t)z * MTOT * 64;
    lg   += (size_t)z * MTOT * 32;
    outp += (size_t)z * MTOT * CCn;

    const int tid = threadIdx.x;
    const int rh0 = blockIdx.x * 64;           // first row-head of block

    if (tid < 64) {
        int rhg = rh0 + tid;
        int h = rhg & 7, rn = rhg >> 3;
        int n = rn & (NNn - 1), b = rn >> 14;
        int yp = n >> 7, xp = n & 127;

        const float* ofp = off + (size_t)rn * 64 + h * 8;
        const float* lgp = lg  + (size_t)rn * 32 + h * 4;
        float4 of0 = *(const float4*)ofp;
        float4 of1 = *(const float4*)(ofp + 4);
        float4 lgv = *(const float4*)lgp;
        float ofx[4] = { of0.x, of0.z, of1.x, of1.z };
        float ofy[4] = { of0.y, of0.w, of1.y, of1.w };

        float mx = fmaxf(fmaxf(lgv.x, lgv.y), fmaxf(lgv.z, lgv.w));
        float e0 = __expf(lgv.x - mx), e1 = __expf(lgv.y - mx);
        float e2 = __expf(lgv.z - mx), e3 = __expf(lgv.w - mx);
        float inv = 1.f / (e0 + e1 + e2 + e3);
        float aw[4] = { e0 * inv, e1 * inv, e2 * inv, e3 * inv };

        unsigned hb = (unsigned)(b * NNn) * 256u + h * 32;
        #pragma unroll
        for (int p = 0; p < 4; ++p) {
            float xs = (float)xp + ofx[p];
            float ys = (float)yp + ofy[p];
            float x0f = floorf(xs), y0f = floorf(ys);
            float lx = xs - x0f, ly = ys - y0f;
            int x0 = (int)x0f, y0 = (int)y0f;
            #pragma unroll
            for (int c = 0; c < 4; ++c) {
                int xi = x0 + (c & 1), yi = y0 + (c >> 1);
                bool valid = (xi >= 0) & (xi < WWn) & (yi >= 0) & (yi < HHn);
                float wgt = valid
                    ? aw[p] * ((c & 1) ? lx : 1.f - lx) * ((c >> 1) ? ly : 1.f - ly)
                    : 0.f;
                int xc = min(max(xi, 0), WWn - 1);
                int yc = min(max(yi, 0), HHn - 1);
                unsigned addr = hb + (unsigned)(yc * WWn + xc) * 256u;
                desc[tid][p * 4 + c] = make_uint2(addr, __float_as_uint(wgt));
            }
        }
    }
    __syncthreads();

    const int rh = tid >> 2;                   // 0..63
    const int q  = tid & 3;                    // 8-channel slice
    const int rhg = rh0 + rh;
    const int h = rhg & 7, rn = rhg >> 3;

    float a[8];
    #pragma unroll
    for (int e = 0; e < 8; ++e) a[e] = 0.f;
    #pragma unroll
    for (int k = 0; k < 16; ++k) {
        uint2 d = desc[rh][k];
        float wgt = __uint_as_float(d.y);
        u16x8 v = *(const u16x8*)(val + d.x + q * 8);
        #pragma unroll
        for (int e = 0; e < 8; ++e)
            a[e] += wgt * bf2f(v[e]);
    }
    u16x8 o;
    #pragma unroll
    for (int e = 0; e < 8; ++e) o[e] = f2bf(a[e]);
    *(u16x8*)(outp + (size_t)rn * CCn + h * 32 + q * 8) = o;
}

// ---------------------------------------------------------------------------
extern "C" void kernel_launch(void* const* d_in, const int* in_sizes, int n_in,
                              void* d_out, int out_size, void* d_ws, size_t ws_size,
                              hipStream_t stream)
{
    const float* cam_bev   = (const float*)d_in[0];
    const float* sat_bev   = (const float*)d_in[1];
    const float* c2s_off_w  = (const float*)d_in[2];
    const float* c2s_off_b  = (const float*)d_in[3];
    const float* c2s_attw_w = (const float*)d_in[4];
    const float* c2s_attw_b = (const float*)d_in[5];
    const float* c2s_vp_w   = (const float*)d_in[6];
    const float* c2s_vp_b   = (const float*)d_in[7];
    const float* c2s_op_w   = (const float*)d_in[8];
    const float* c2s_op_b   = (const float*)d_in[9];
    const float* s2c_off_w  = (const float*)d_in[10];
    const float* s2c_off_b  = (const float*)d_in[11];
    const float* s2c_attw_w = (const float*)d_in[12];
    const float* s2c_attw_b = (const float*)d_in[13];
    const float* s2c_vp_w   = (const float*)d_in[14];
    const float* s2c_vp_b   = (const float*)d_in[15];
    const float* s2c_op_w   = (const float*)d_in[16];
    const float* s2c_op_b   = (const float*)d_in[17];
    const float* ln1_g = (const float*)d_in[18];
    const float* ln1_b = (const float*)d_in[19];
    const float* ln2_g = (const float*)d_in[20];
    const float* ln2_b = (const float*)d_in[21];
    const float* lnf_g = (const float*)d_in[22];
    const float* lnf_b = (const float*)d_in[23];
    const float* ffn1_w = (const float*)d_in[24];
    const float* ffn1_b = (const float*)d_in[25];
    const float* ffn2_w = (const float*)d_in[26];
    const float* ffn2_b = (const float*)d_in[27];
    const float* g1_w  = (const float*)d_in[28];
    const float* bn_g  = (const float*)d_in[29];
    const float* bn_b  = (const float*)d_in[30];
    const float* g2_w  = (const float*)d_in[31];
    const float* g2_b  = (const float*)d_in[32];

    char* base = (char*)d_ws;
    size_t off = 0;
    auto alloc = [&](size_t bytes) -> void* {
        void* p = base + off;
        off += (bytes + 255) & ~(size_t)255;
        return p;
    };

    u16*   qcam   = (u16*)  alloc((size_t)MTOT * CCn * 2 * 2);   // qcam|qsat contiguous
    u16*   qsat   = qcam + (size_t)MTOT * CCn;
    u16*   valb   = (u16*)  alloc((size_t)MTOT * CCn * 2 * 2);   // pair
    u16*   sampb  = (u16*)  alloc((size_t)MTOT * CCn * 2 * 2);   // pair (33.55MB)
    float* offb   = (float*)alloc((size_t)MTOT * 64 * 4 * 2);    // pair (16.78MB)
    float* attwb  = (float*)alloc((size_t)MTOT * 32 * 4 * 2);    // pair
    size_t padBytes = (size_t)BBn * PADW * PADW * 512 * 2;       // 34.6MB
    u16*   pad    = (u16*)  alloc(padBytes);
    u16*   hbuf   = (u16*)  alloc((size_t)MTOT * 128 * 2);
    u16*   convpart = (u16*)alloc((size_t)3 * MTOT * 128 * 2);   // 25.2MB
    u16*   wbase  = (u16*)  alloc((size_t)1212416 * 2);
    float* biasbf = (float*)alloc((size_t)2240 * 4);
    // weight slices
    u16* wvp = wbase;                 // pair, stride 65536
    u16* wop = wbase + 131072;        // pair, stride 65536
    u16* wf1 = wbase + 262144;
    u16* wf2 = wbase + 393216;
    u16* woa = wbase + 524288;        // pair, stride 32768
    u16* wcv = wbase + 589824;
    u16* wg2 = wbase + 1179648;
    // aliases (temporally disjoint)
    u16*   fused_bf = valb;              // valb dead after sampling
    u16*   midb     = qcam;              // qcam/qsat dead after op-pair (MTOT*512 bf16)

    dim3 blk(256);
    ZOff zz{0, 0, 0, 0, 0, 0, 0, 0, 0};

    // ---------- fused prologue: tcvt | repack | zring ----------
    prologue_k<<<9100, blk, 0, stream>>>(
        cam_bev, sat_bev, qcam, qsat,
        c2s_vp_w, c2s_op_w, s2c_vp_w, s2c_op_w,
        ffn1_w, ffn2_w, c2s_off_w, c2s_attw_w,
        s2c_off_w, s2c_attw_w, g1_w, g2_w,
        c2s_vp_b, s2c_vp_b, c2s_op_b, s2c_op_b,
        c2s_off_b, c2s_attw_b, s2c_off_b, s2c_attw_b,
        ln1_g, ln1_b, ln2_g, ln2_b,
        wbase, biasbf, pad);

    // ---------- fused value + offset/attw projections ----------
    vpoa_k<<<1536, blk, 0, stream>>>(qcam, wvp, woa, biasbf, valb, offb, attwb);

    // ---------- deformable sampling (both streams, 2-phase, 16B gathers) ----
    sample_k<<<dim3(4096, 1, 2), blk, 0, stream>>>(valb, offb, attwb, sampb);
    // ---------- output projections + residual + LN -> pad image ----------
    {
        ZOff zo{ (long)MTOT * CCn, 65536, 256, 0, 0, 0, (long)MTOT * CCn, 512, 256 };
        mgemm<64, 256, 4, 7, 256><<<dim3(1, 512, 2), blk, 0, stream>>>(
            sampb, wop, biasbf + 512, 256, 256,
            nullptr, nullptr, pad, nullptr, qcam, biasbf + 1216, biasbf + 1472, 0, zo);
    }
    // ---------- gating conv: BK=32 dbuf, split-K=3, bf16 partials ----------
    conv_k<3><<<dim3(1, 256, 3), blk, 0, stream>>>(pad, wcv, convpart);
    combine_k<<<4096, blk, 0, stream>>>(convpart, bn_g, bn_b, hbuf);

    // ---------- 1x1 conv + sigmoid + gated fusion (bf16 out, BM=64) ----------
    mgemm<64, 128, 2, 4, 128><<<dim3(2, 512, 1), blk, 0, stream>>>(
        hbuf, wg2, g2_b, 128, 256,
        nullptr, nullptr, fused_bf, pad, nullptr, nullptr, nullptr, 0, zz);

    // ---------- FFN ----------
    mgemm<128, 128, 2, 5, 256><<<dim3(4, 256, 1), blk, 0, stream>>>(
        fused_bf, wf1, ffn1_b, 256, 512,
        nullptr, nullptr, midb, nullptr, nullptr, nullptr, nullptr, 0, zz);
    // ffn2 + final LN + transpose to (B,C,N) + cam residual (EPI 9, bf16 resid)
    mgemm<64, 256, 4, 9, 512><<<dim3(1, 512, 1), blk, 0, stream>>>(
        midb, wf2, ffn2_b, 512, 256,
        (float*)d_out, (float*)cam_bev, nullptr, nullptr, fused_bf, lnf_g, lnf_b, 0, zz);
}

// Round 22
// 263.924 us; speedup vs baseline: 1.0742x; 1.0213x over previous
//
#include <hip/hip_runtime.h>
#include <hip/hip_bf16.h>
#include <cstddef>

#define BBn  2
#define CCn  256
#define HHn  128
#define WWn  128
#define NNn  (HHn*WWn)        // 16384
#define MTOT (BBn*NNn)        // 32768
#define PADW 130

typedef unsigned short u16;
typedef __attribute__((ext_vector_type(8))) short bf8v;
typedef __attribute__((ext_vector_type(8))) unsigned short u16x8;
typedef __attribute__((ext_vector_type(4))) float f4v;

typedef __attribute__((address_space(1))) const void gvoid_t;
typedef __attribute__((address_space(3))) void svoid_t;
#define ASYNC16(g, l) __builtin_amdgcn_global_load_lds((gvoid_t*)(g), (svoid_t*)(l), 16, 0, 0)

__device__ __forceinline__ u16 f2bf(float f) {
    __hip_bfloat16 h = __float2bfloat16(f);
    return *reinterpret_cast<u16*>(&h);
}
__device__ __forceinline__ float bf2f(u16 h) {
    return __uint_as_float(((unsigned)h) << 16);
}

// z-offsets (elements), applied scaled by blockIdx.z
struct ZOff {
    long a, w, bia, f1, f2, b1, r, p;
    int ch;
};

// ---------------------------------------------------------------------------
// bf16 MFMA GEMM, tile BM x BN, BK=32, double-buffered LDS (stage-ahead),
// both-sides XOR swizzle: chunk' = chunk ^ ((row>>1)&3).
// EPI: 4 sigmoid-gate (bf16 out) | 5 ReLU->bf16
//      7 resid(bf16)-init + rowLN -> pad bf16 | 9 resid(bf16)-init + rowLN -> (B,C,N) + cam
// ---------------------------------------------------------------------------
template<int BM, int BN, int WC, int EPI, int KK>
__global__ __launch_bounds__(256)
void mgemm(const u16* __restrict__ A, const u16* __restrict__ Wt,
           const float* __restrict__ bias, int ldw, int Nc,
           float* __restrict__ outf, float* __restrict__ outf2,
           u16* __restrict__ outb, const u16* __restrict__ img,
           const void* __restrict__ resid,
           const float* __restrict__ p0, const float* __restrict__ p1,
           int choff, ZOff zo)
{
    constexpr int WR = 4 / WC;
    constexpr int MROWS = BM / WR;       // rows per wave
    constexpr int MI = MROWS / 16;
    constexpr int AT = BM / 64;          // A staging chunks per thread
    constexpr int BT = BN / 64;
    constexpr int NSTEPS = KK / 32;

    __shared__ __align__(16) u16 As[2 * BM * 32];
    __shared__ __align__(16) u16 Bs[2 * BN * 32];
    __shared__ float red[4][64][2];      // LN cross-wave partials (EPI 7/9)

    const int z = blockIdx.z;
    if (z) {
        A += (long)z * zo.a; Wt += (long)z * zo.w;
        if (bias)  bias  += (long)z * zo.bia;
        if (outf)  outf  += (long)z * zo.f1;
        if (outf2) outf2 += (long)z * zo.f2;
        if (outb)  outb  += (long)z * zo.b1;
        if (p0)    p0    += (long)z * zo.p;
        if (p1)    p1    += (long)z * zo.p;
        choff += z * zo.ch;
    }

    const int tid  = threadIdx.x;
    const int lane = tid & 63;
    const int w    = tid >> 6;
    const int wr   = w / WC, wc = w % WC;
    const int by = blockIdx.y;
    const int m0 = by * BM;
    const int n0 = blockIdx.x * BN;
    const int lr = lane & 15, lq = lane >> 4;

    // staging source pointers (source chunk pre-swizzled; LDS dest linear)
    const u16* gA[AT]; int loA[AT];
    #pragma unroll
    for (int t = 0; t < AT; ++t) {
        int c = t * 256 + tid; int row = c >> 2; int part = c & 3;
        int pg = part ^ ((row >> 1) & 3);
        gA[t] = A + (size_t)(m0 + row) * KK + pg * 8;
        loA[t] = c * 8;
    }
    const u16* gB[BT]; int loB[BT];
    #pragma unroll
    for (int t = 0; t < BT; ++t) {
        int c = t * 256 + tid; int row = c >> 2; int part = c & 3;
        int pg = part ^ ((row >> 1) & 3);
        gB[t] = Wt + (size_t)(n0 + row) * ldw + pg * 8;
        loB[t] = c * 8;
    }

    // accumulator (residual+bias init for LN epilogues; WR==1 there)
    f4v acc[MI][4];
    if constexpr (EPI == 7 || EPI == 9) {
        const u16* r16 = (const u16*)resid + (EPI == 7 ? (long)z * zo.r : 0);
        #pragma unroll
        for (int j = 0; j < 4; ++j) {
            int n = wc * 64 + j * 16 + lr;
            float bj = bias[n];
            #pragma unroll
            for (int i = 0; i < MI; ++i)
                #pragma unroll
                for (int r = 0; r < 4; ++r) {
                    int m = m0 + i * 16 + lq * 4 + r;
                    acc[i][j][r] = bf2f(r16[(size_t)m * 256 + n]) + bj;
                }
        }
    } else {
        #pragma unroll
        for (int i = 0; i < MI; ++i)
            #pragma unroll
            for (int j = 0; j < 4; ++j)
                acc[i][j] = (f4v){0.f, 0.f, 0.f, 0.f};
    }

    auto stageG = [&](int s, int buf) {
        int k0 = s * 32;
        #pragma unroll
        for (int t = 0; t < AT; ++t)
            ASYNC16(gA[t] + k0, (u16*)As + buf * (BM * 32) + loA[t]);
        #pragma unroll
        for (int t = 0; t < BT; ++t)
            ASYNC16(gB[t] + k0, (u16*)Bs + buf * (BN * 32) + loB[t]);
    };
    auto computeStep = [&](int s) {
        const u16* Ab = As + (s & 1) * (BM * 32);
        const u16* Bb = Bs + (s & 1) * (BN * 32);
        bf8v af[MI], bv[4];
        #pragma unroll
        for (int i = 0; i < MI; ++i) {
            int row = wr * MROWS + i * 16 + lr;
            af[i] = *(const bf8v*)&Ab[row * 32 + ((lq ^ ((row >> 1) & 3)) << 3)];
        }
        #pragma unroll
        for (int j = 0; j < 4; ++j) {
            int row = wc * 64 + j * 16 + lr;
            bv[j] = *(const bf8v*)&Bb[row * 32 + ((lq ^ ((row >> 1) & 3)) << 3)];
        }
        #pragma unroll
        for (int i = 0; i < MI; ++i)
            #pragma unroll
            for (int j = 0; j < 4; ++j)
                acc[i][j] = __builtin_amdgcn_mfma_f32_16x16x32_bf16(af[i], bv[j], acc[i][j], 0, 0, 0);
    };

    stageG(0, 0);
    __syncthreads();
    for (int s = 0; s < NSTEPS - 1; ++s) {
        stageG(s + 1, (s + 1) & 1);
        computeStep(s);
        __syncthreads();
    }
    computeStep(NSTEPS - 1);

    // -------------------- epilogue --------------------
    if constexpr (EPI == 7 || EPI == 9) {
        float g4[4], b4[4];
        #pragma unroll
        for (int j = 0; j < 4; ++j) {
            int n = wc * 64 + j * 16 + lr;
            g4[j] = p0[n]; b4[j] = p1[n];
        }
        #pragma unroll
        for (int i = 0; i < MI; ++i)
            #pragma unroll
            for (int r = 0; r < 4; ++r) {
                float p = 0.f, p2 = 0.f;
                #pragma unroll
                for (int j = 0; j < 4; ++j) { float v = acc[i][j][r]; p += v; p2 += v * v; }
                p += __shfl_xor(p, 1, 16);  p2 += __shfl_xor(p2, 1, 16);
                p += __shfl_xor(p, 2, 16);  p2 += __shfl_xor(p2, 2, 16);
                p += __shfl_xor(p, 4, 16);  p2 += __shfl_xor(p2, 4, 16);
                p += __shfl_xor(p, 8, 16);  p2 += __shfl_xor(p2, 8, 16);
                if (lr == 0) {
                    int row = i * 16 + lq * 4 + r;
                    red[w][row][0] = p; red[w][row][1] = p2;
                }
            }
        __syncthreads();
        #pragma unroll
        for (int i = 0; i < MI; ++i) {
            float mean4[4], rstd4[4];
            #pragma unroll
            for (int r = 0; r < 4; ++r) {
                int row = i * 16 + lq * 4 + r;
                float s  = red[0][row][0] + red[1][row][0] + red[2][row][0] + red[3][row][0];
                float s2 = red[0][row][1] + red[1][row][1] + red[2][row][1] + red[3][row][1];
                float mean = s * (1.f / 256.f);
                float var  = s2 * (1.f / 256.f) - mean * mean;
                mean4[r] = mean;
                rstd4[r] = rsqrtf(var + 1e-5f);
            }
            if constexpr (EPI == 7) {
                #pragma unroll
                for (int r = 0; r < 4; ++r) {
                    int m = m0 + i * 16 + lq * 4 + r;
                    int b = m >> 14, sp = m & (NNn - 1);
                    size_t pb = (((size_t)b * PADW + (sp >> 7) + 1) * PADW + (sp & 127) + 1) * 512 + choff;
                    #pragma unroll
                    for (int j = 0; j < 4; ++j) {
                        int n = wc * 64 + j * 16 + lr;
                        outb[pb + n] = f2bf((acc[i][j][r] - mean4[r]) * rstd4[r] * g4[j] + b4[j]);
                    }
                }
            } else {
                // transposed write to (B,C,N) + cam residual (outf2 = cam_bev)
                int mb = m0 + i * 16 + lq * 4;
                int b = mb >> 14, sp = mb & (NNn - 1);
                #pragma unroll
                for (int j = 0; j < 4; ++j) {
                    int n = wc * 64 + j * 16 + lr;
                    size_t oi = ((size_t)b * 256 + n) * NNn + sp;
                    float4 cv = *(const float4*)&outf2[oi];
                    float4 o;
                    o.x = (acc[i][j][0] - mean4[0]) * rstd4[0] * g4[j] + b4[j] + cv.x;
                    o.y = (acc[i][j][1] - mean4[1]) * rstd4[1] * g4[j] + b4[j] + cv.y;
                    o.z = (acc[i][j][2] - mean4[2]) * rstd4[2] * g4[j] + b4[j] + cv.z;
                    o.w = (acc[i][j][3] - mean4[3]) * rstd4[3] * g4[j] + b4[j] + cv.w;
                    *(float4*)&outf[oi] = o;
                }
            }
        }
        return;
    }

    float bj[4]; int ncol[4];
    #pragma unroll
    for (int j = 0; j < 4; ++j) {
        int n = n0 + wc * 64 + j * 16 + lr;
        ncol[j] = n;
        if constexpr (EPI == 4 || EPI == 5) bj[j] = bias[n];
    }
    #pragma unroll
    for (int i = 0; i < MI; ++i) {
        #pragma unroll
        for (int r = 0; r < 4; ++r) {
            int m = m0 + wr * MROWS + i * 16 + lq * 4 + r;
            size_t pb = 0;
            if constexpr (EPI == 4) {
                int b = m >> 14, sp = m & (NNn - 1);
                pb = (((size_t)b * PADW + (sp >> 7) + 1) * PADW + (sp & 127) + 1) * 512;
            }
            #pragma unroll
            for (int j = 0; j < 4; ++j) {
                int n = ncol[j];
                float v = acc[i][j][r];
                size_t oi = (size_t)m * Nc + n;
                if constexpr (EPI == 4) {
                    float vv = v + bj[j];
                    float g = 1.f / (1.f + __expf(-vv));
                    float f = g * bf2f(img[pb + n]) + (1.f - g) * bf2f(img[pb + 256 + n]);
                    outb[oi] = f2bf(f);
                } else if constexpr (EPI == 5) {
                    outb[oi] = f2bf(fmaxf(v + bj[j], 0.f));
                }
            }
        }
    }
}

// ---------------------------------------------------------------------------
// fused vp + oa projections, one launch. BM=BN=128, BK=32 dbuf, KK=256.
// ---------------------------------------------------------------------------
__global__ __launch_bounds__(256)
void vpoa_k(const u16* __restrict__ qcam, const u16* __restrict__ wvp,
            const u16* __restrict__ woa, const float* __restrict__ biasbf,
            u16* __restrict__ valb, float* __restrict__ offb,
            float* __restrict__ attwb)
{
    __shared__ __align__(16) u16 As[2 * 128 * 32];
    __shared__ __align__(16) u16 Bs[2 * 128 * 32];

    const int bx = blockIdx.x;
    int job, zs, by, n0;
    if (bx < 1024) { job = 0; zs = bx >> 9; int r = bx & 511; n0 = (r & 1) * 128; by = r >> 1; }
    else           { job = 1; int r = bx - 1024; zs = r >> 8; by = r & 255; n0 = 0; }

    const u16* A  = job == 0 ? qcam + (size_t)(1 - zs) * MTOT * CCn
                             : qcam + (size_t)zs * MTOT * CCn;
    const u16* Wt = job == 0 ? wvp + zs * 65536 : woa + zs * 32768;

    const int tid  = threadIdx.x;
    const int lane = tid & 63;
    const int w    = tid >> 6;
    const int wr   = w >> 1, wc = w & 1;
    const int m0 = by * 128;
    const int lr = lane & 15, lq = lane >> 4;

    const u16* gA[2]; int loA[2];
    const u16* gB[2]; int loB[2];
    #pragma unroll
    for (int t = 0; t < 2; ++t) {
        int c = t * 256 + tid; int row = c >> 2; int part = c & 3;
        int pg = part ^ ((row >> 1) & 3);
        gA[t] = A + (size_t)(m0 + row) * 256 + pg * 8;
        gB[t] = Wt + (size_t)(n0 + row) * 256 + pg * 8;
        loA[t] = c * 8; loB[t] = c * 8;
    }

    f4v acc[4][4];
    #pragma unroll
    for (int i = 0; i < 4; ++i)
        #pragma unroll
        for (int j = 0; j < 4; ++j)
            acc[i][j] = (f4v){0.f, 0.f, 0.f, 0.f};

    auto stageG = [&](int s, int buf) {
        int k0 = s * 32;
        #pragma unroll
        for (int t = 0; t < 2; ++t) {
            ASYNC16(gA[t] + k0, (u16*)As + buf * (128 * 32) + loA[t]);
            ASYNC16(gB[t] + k0, (u16*)Bs + buf * (128 * 32) + loB[t]);
        }
    };
    auto computeStep = [&](int s) {
        const u16* Ab = As + (s & 1) * (128 * 32);
        const u16* Bb = Bs + (s & 1) * (128 * 32);
        bf8v af[4], bv[4];
        #pragma unroll
        for (int i = 0; i < 4; ++i) {
            int row = wr * 64 + i * 16 + lr;
            af[i] = *(const bf8v*)&Ab[row * 32 + ((lq ^ ((row >> 1) & 3)) << 3)];
        }
        #pragma unroll
        for (int j = 0; j < 4; ++j) {
            int row = wc * 64 + j * 16 + lr;
            bv[j] = *(const bf8v*)&Bb[row * 32 + ((lq ^ ((row >> 1) & 3)) << 3)];
        }
        #pragma unroll
        for (int i = 0; i < 4; ++i)
            #pragma unroll
            for (int j = 0; j < 4; ++j)
                acc[i][j] = __builtin_amdgcn_mfma_f32_16x16x32_bf16(af[i], bv[j], acc[i][j], 0, 0, 0);
    };

    stageG(0, 0);
    __syncthreads();
    for (int s = 0; s < 7; ++s) {
        stageG(s + 1, (s + 1) & 1);
        computeStep(s);
        __syncthreads();
    }
    computeStep(7);

    if (job == 0) {
        u16* outb = valb + (size_t)zs * MTOT * CCn;
        const float* bias = biasbf + zs * 256;
        float bj[4]; int ncol[4];
        #pragma unroll
        for (int j = 0; j < 4; ++j) {
            int n = n0 + wc * 64 + j * 16 + lr;
            ncol[j] = n; bj[j] = bias[n];
        }
        #pragma unroll
        for (int i = 0; i < 4; ++i)
            #pragma unroll
            for (int r = 0; r < 4; ++r) {
                int m = m0 + wr * 64 + i * 16 + lq * 4 + r;
                #pragma unroll
                for (int j = 0; j < 4; ++j)
                    outb[(size_t)m * 256 + ncol[j]] = f2bf(acc[i][j][r] + bj[j]);
            }
    } else {
        float* of = offb + (size_t)zs * MTOT * 64;
        float* aw = attwb + (size_t)zs * MTOT * 32;
        const float* p0 = biasbf + 1024 + zs * 96;
        const float* p1 = biasbf + 1088 + zs * 96;
        #pragma unroll
        for (int i = 0; i < 4; ++i)
            #pragma unroll
            for (int r = 0; r < 4; ++r) {
                int m = m0 + wr * 64 + i * 16 + lq * 4 + r;
                #pragma unroll
                for (int j = 0; j < 4; ++j) {
                    int n = wc * 64 + j * 16 + lr;
                    float v = acc[i][j][r];
                    if (n < 64)      of[(size_t)m * 64 + n]        = v + p0[n];
                    else if (n < 96) aw[(size_t)m * 32 + (n - 64)] = v + p1[n - 64];
                }
            }
    }
}

// ---------------------------------------------------------------------------
// dedicated conv kernel: 128x128 tile, BK=32, double-buffered stage-ahead
// (one barrier/step), both-sides XOR swizzle chunk^=((row>>1)&3).
// split-K = 3 (3 taps per z). bf16 partial out. grid (1, 256, 3).
// ---------------------------------------------------------------------------
template<int TAPS>
__global__ __launch_bounds__(256)
void conv_k(const u16* __restrict__ img, const u16* __restrict__ Wt,
            u16* __restrict__ outp)
{
    constexpr int NS = TAPS * 16;
    __shared__ __align__(16) u16 As[2 * 128 * 32];
    __shared__ __align__(16) u16 Bs[2 * 128 * 32];

    const int z = blockIdx.z;
    outp += (size_t)z * MTOT * 128;
    const int tid = threadIdx.x;
    const int lane = tid & 63;
    const int w = tid >> 6;
    const int wr = w >> 1, wc = w & 1;
    int by = blockIdx.y;
    by = ((by & 7) << 5) | (by >> 3);       // XCD swizzle (256 = 8*32)
    const int m0 = by * 128;
    const int lr = lane & 15, lq = lane >> 4;

    // staging: 2 chunks/thread each; c = t*256+tid, row=c>>2, part=c&3
    const u16* abase[2]; const u16* bbase[2]; int ldsOff[2];
    #pragma unroll
    for (int t = 0; t < 2; ++t) {
        int c = t * 256 + tid;
        int row = c >> 2, part = c & 3;
        int pg = part ^ ((row >> 1) & 3);
        ldsOff[t] = c * 8;
        int m = m0 + row; int b = m >> 14; int sp = m & (NNn - 1);
        long cb = ((long)b * PADW + (sp >> 7)) * PADW + (sp & 127);
        abase[t] = img + cb * 512 + pg * 8;
        bbase[t] = Wt + (size_t)row * 4608 + pg * 8;
    }

    long adel[TAPS]; int bdel[TAPS];
    #pragma unroll
    for (int tt = 0; tt < TAPS; ++tt) {
        int tap = z * TAPS + tt;
        int dy = tap / 3, dx = tap - dy * 3;
        adel[tt] = (long)(dy * PADW + dx) * 512;
        bdel[tt] = tap * 512;
    }

    f4v acc[4][4];
    #pragma unroll
    for (int i = 0; i < 4; ++i)
        #pragma unroll
        for (int j = 0; j < 4; ++j)
            acc[i][j] = (f4v){0.f, 0.f, 0.f, 0.f};

    auto stage = [&](int s, int buf) {
        int tt = s >> 4;
        int ci = (s & 15) * 32;
        #pragma unroll
        for (int t = 0; t < 2; ++t) {
            ASYNC16(abase[t] + adel[tt] + ci, (u16*)As + buf * (128 * 32) + ldsOff[t]);
            ASYNC16(bbase[t] + bdel[tt] + ci, (u16*)Bs + buf * (128 * 32) + ldsOff[t]);
        }
    };
    auto computeStep = [&](int s) {
        const u16* Ab = As + (s & 1) * (128 * 32);
        const u16* Bb = Bs + (s & 1) * (128 * 32);
        bf8v af[4], bv[4];
        #pragma unroll
        for (int i = 0; i < 4; ++i) {
            int row = wr * 64 + i * 16 + lr;
            af[i] = *(const bf8v*)&Ab[row * 32 + ((lq ^ ((row >> 1) & 3)) << 3)];
        }
        #pragma unroll
        for (int j = 0; j < 4; ++j) {
            int row = wc * 64 + j * 16 + lr;
            bv[j] = *(const bf8v*)&Bb[row * 32 + ((lq ^ ((row >> 1) & 3)) << 3)];
        }
        #pragma unroll
        for (int i = 0; i < 4; ++i)
            #pragma unroll
            for (int j = 0; j < 4; ++j)
                acc[i][j] = __builtin_amdgcn_mfma_f32_16x16x32_bf16(af[i], bv[j], acc[i][j], 0, 0, 0);
    };

    stage(0, 0);
    __syncthreads();
    #pragma unroll 4
    for (int s = 0; s < NS - 1; ++s) {
        stage(s + 1, (s + 1) & 1);
        computeStep(s);
        __syncthreads();
    }
    computeStep(NS - 1);

    #pragma unroll
    for (int i = 0; i < 4; ++i)
        #pragma unroll
        for (int r = 0; r < 4; ++r) {
            int m = m0 + wr * 64 + i * 16 + lq * 4 + r;
            #pragma unroll
            for (int j = 0; j < 4; ++j) {
                int n = wc * 64 + j * 16 + lr;
                outp[(size_t)m * 128 + n] = f2bf(acc[i][j][r]);
            }
        }
}

// ---------------------------------------------------------------------------
// split-K combine (3 bf16 partials) + BN + ReLU -> bf16
// ---------------------------------------------------------------------------
__global__ __launch_bounds__(256)
void combine_k(const u16* __restrict__ part, const float* __restrict__ bng,
               const float* __restrict__ bnb, u16* __restrict__ hb)
{
    const float bnscale = rsqrtf(1.0f + 1e-5f);
    int i = (blockIdx.x * 256 + threadIdx.x) * 4;   // over MTOT*128
    int n = i & 127;
    float s0 = 0.f, s1 = 0.f, s2 = 0.f, s3 = 0.f;
    #pragma unroll
    for (int p = 0; p < 3; ++p) {
        ushort4 a = *(const ushort4*)&part[(size_t)p * MTOT * 128 + i];
        s0 += bf2f(a.x); s1 += bf2f(a.y); s2 += bf2f(a.z); s3 += bf2f(a.w);
    }
    ushort4 o;
    o.x = f2bf(fmaxf(s0 * bnscale * bng[n + 0] + bnb[n + 0], 0.f));
    o.y = f2bf(fmaxf(s1 * bnscale * bng[n + 1] + bnb[n + 1], 0.f));
    o.z = f2bf(fmaxf(s2 * bnscale * bng[n + 2] + bnb[n + 2], 0.f));
    o.w = f2bf(fmaxf(s3 * bnscale * bng[n + 3] + bnb[n + 3], 0.f));
    *(ushort4*)&hb[i] = o;
}

// ---------------------------------------------------------------------------
// fused prologue: tcvt (4096 blocks) | repack (4746 blocks) | zring (258)
// flat grid 9100 x 256 threads.
// ---------------------------------------------------------------------------
__global__ __launch_bounds__(256)
void prologue_k(const float* __restrict__ cam, const float* __restrict__ sat,
                u16* __restrict__ qcam, u16* __restrict__ qsat,
                const float* __restrict__ vp1, const float* __restrict__ op1,
                const float* __restrict__ vp2, const float* __restrict__ op2,
                const float* __restrict__ f1w, const float* __restrict__ f2w,
                const float* __restrict__ of1, const float* __restrict__ aw1,
                const float* __restrict__ of2, const float* __restrict__ aw2,
                const float* __restrict__ g1,  const float* __restrict__ g2,
                const float* __restrict__ vpb1, const float* __restrict__ vpb2,
                const float* __restrict__ opb1, const float* __restrict__ opb2,
                const float* __restrict__ ofb1, const float* __restrict__ awb1,
                const float* __restrict__ ofb2, const float* __restrict__ awb2,
                const float* __restrict__ l1g, const float* __restrict__ l1b,
                const float* __restrict__ l2g, const float* __restrict__ l2b,
                u16* __restrict__ wb, float* __restrict__ bb,
                u16* __restrict__ pad)
{
    __shared__ float t[64][65];
    const int bx = blockIdx.x;
    const int tid = threadIdx.x;

    if (bx < 4096) {
        // -------- tcvt --------
        int x = bx & 3, y = (bx >> 2) & 255, zz = bx >> 10;
        const float* src = (zz < 2) ? cam : sat;
        u16* dst = (zz < 2) ? qcam : qsat;
        int b = zz & 1;
        int c0 = x * 64, sp0 = y * 64;
        #pragma unroll
        for (int it = 0; it < 16; ++it) {
            int idx = it * 256 + tid;
            int cl = idx >> 6, sl = idx & 63;
            t[cl][sl] = src[((size_t)(b * CCn + c0 + cl)) * NNn + sp0 + sl];
        }
        __syncthreads();
        #pragma unroll
        for (int it = 0; it < 16; ++it) {
            int idx = it * 256 + tid;
            int sl = idx >> 6, cl = idx & 63;
            dst[((size_t)(b * NNn + sp0 + sl)) * CCn + c0 + cl] = f2bf(t[cl][sl]);
        }
        return;
    }
    if (bx < 8842) {
        // -------- repack --------
        int i = (bx - 4096) * 256 + tid;
        if (i >= 1212416 + 2240) return;
        if (i >= 1212416) {
            int j = i - 1212416;
            float v;
            if      (j < 256)  v = vpb1[j];
            else if (j < 512)  v = vpb2[j - 256];
            else if (j < 768)  v = opb1[j - 512];
            else if (j < 1024) v = opb2[j - 768];
            else if (j < 1088) v = ofb1[j - 1024];
            else if (j < 1120) v = awb1[j - 1088];
            else if (j < 1184) v = ofb2[j - 1120];
            else if (j < 1216) v = awb2[j - 1184];
            else if (j < 1472) v = l1g[j - 1216];
            else if (j < 1728) v = l1b[j - 1472];
            else if (j < 1984) v = l2g[j - 1728];
            else               v = l2b[j - 1984];
            bb[j] = v;
            return;
        }
        float v;
        if (i < 262144) {
            const float* src[4] = { vp1, vp2, op1, op2 };
            int q = i >> 16, j = i & 65535;
            int n = j >> 8, k = j & 255;
            v = src[q][(size_t)k * 256 + n];
        } else if (i < 393216) {
            int j = i - 262144; int n = j >> 8, k = j & 255;      // [512][256]
            v = f1w[(size_t)k * 512 + n];
        } else if (i < 524288) {
            int j = i - 393216; int n = j >> 9, k = j & 511;      // [256][512]
            v = f2w[(size_t)k * 256 + n];
        } else if (i < 589824) {
            int jj = i - 524288; int hh = jj >> 15; int j = jj & 32767;
            int n = j >> 8, k = j & 255;                          // [128][256]
            const float* ofw = hh ? of2 : of1;
            const float* aww = hh ? aw2 : aw1;
            if (n < 64)      v = ofw[(size_t)k * 64 + n];
            else if (n < 96) v = aww[(size_t)k * 32 + (n - 64)];
            else             v = 0.f;
        } else if (i < 1179648) {
            int j = i - 589824; int co = j / 4608, k = j - co * 4608;
            int tap = k >> 9, ci = k & 511;
            v = g1[((size_t)co * 512 + ci) * 9 + tap];
        } else {
            int j = i - 1179648; int n = j >> 7, k = j & 127;     // [256][128]
            v = g2[(size_t)n * 128 + k];
        }
        wb[i] = f2bf(v);
        return;
    }
    // -------- zring --------
    {
        int i = (bx - 8842) * 256 + tid;
        if (i >= 66048) return;
        int e = i * 8;
        const int per_b = 264192;
        int b = e / per_b; int r = e - b * per_b;
        long off;
        if (r < 66560)       { int x = r >> 9, c = r & 511;                 off = (((long)b * PADW + 0)   * PADW + x)   * 512 + c; }
        else if (r < 133120) { int r2 = r - 66560;  int x = r2 >> 9, c = r2 & 511; off = (((long)b * PADW + 129) * PADW + x)   * 512 + c; }
        else if (r < 198656) { int r2 = r - 133120; int y = (r2 >> 9) + 1, c = r2 & 511; off = (((long)b * PADW + y)   * PADW + 0)   * 512 + c; }
        else                 { int r2 = r - 198656; int y = (r2 >> 9) + 1, c = r2 & 511; off = (((long)b * PADW + y)   * PADW + 129) * 512 + c; }
        *(u16x8*)(pad + off) = (u16x8){0, 0, 0, 0, 0, 0, 0, 0};
    }
}

// ---------------------------------------------------------------------------
// deformable sampling, two-phase (descriptors in LDS, coalesced gathers).
// 4 lanes per (row,head), ushort8 (16B) loads. block = 64 rh; grid (4096,1,2).
// XCD-chunked bijective swizzle (4096 = 8 x 512): each XCD works one
// contiguous 1/8 of image rows -> gather window ~2.7MB fits private L2.
// ---------------------------------------------------------------------------
__global__ __launch_bounds__(256)
void sample_k(const u16* __restrict__ val, const float* __restrict__ off,
              const float* __restrict__ lg, u16* __restrict__ outp)
{
    __shared__ uint2 desc[64][17];     // padded stride: avoid fixed-k bank camp

    int z = blockIdx.z;
    val  += (size_t)z * MTOT * CCn;
    off  += (size_t)z * MTOT * 64;
    lg   += (size_t)z * MTOT * 32;
    outp += (size_t)z * MTOT * CCn;

    const int tid = threadIdx.x;
    int bx = blockIdx.x;
    bx = ((bx & 7) << 9) | (bx >> 3);          // XCD-bijective swizzle
    const int rh0 = bx * 64;                   // first row-head of block

    if (tid < 64) {
        int rhg = rh0 + tid;
        int h = rhg & 7, rn = rhg >> 3;
        int n = rn & (NNn - 1), b = rn >> 14;
        int yp = n >> 7, xp = n & 127;

        const float* ofp = off + (size_t)rn * 64 + h * 8;
        const float* lgp = lg  + (size_t)rn * 32 + h * 4;
        float4 of0 = *(const float4*)ofp;
        float4 of1 = *(const float4*)(ofp + 4);
        float4 lgv = *(const float4*)lgp;
        float ofx[4] = { of0.x, of0.z, of1.x, of1.z };
        float ofy[4] = { of0.y, of0.w, of1.y, of1.w };

        float mx = fmaxf(fmaxf(lgv.x, lgv.y), fmaxf(lgv.z, lgv.w));
        float e0 = __expf(lgv.x - mx), e1 = __expf(lgv.y - mx);
        float e2 = __expf(lgv.z - mx), e3 = __expf(lgv.w - mx);
        float inv = 1.f / (e0 + e1 + e2 + e3);
        float aw[4] = { e0 * inv, e1 * inv, e2 * inv, e3 * inv };

        unsigned hb = (unsigned)(b * NNn) * 256u + h * 32;
        #pragma unroll
        for (int p = 0; p < 4; ++p) {
            float xs = (float)xp + ofx[p];
            float ys = (float)yp + ofy[p];
            float x0f = floorf(xs), y0f = floorf(ys);
            float lx = xs - x0f, ly = ys - y0f;
            int x0 = (int)x0f, y0 = (int)y0f;
            #pragma unroll
            for (int c = 0; c < 4; ++c) {
                int xi = x0 + (c & 1), yi = y0 + (c >> 1);
                bool valid = (xi >= 0) & (xi < WWn) & (yi >= 0) & (yi < HHn);
                float wgt = valid
                    ? aw[p] * ((c & 1) ? lx : 1.f - lx) * ((c >> 1) ? ly : 1.f - ly)
                    : 0.f;
                int xc = min(max(xi, 0), WWn - 1);
                int yc = min(max(yi, 0), HHn - 1);
                unsigned addr = hb + (unsigned)(yc * WWn + xc) * 256u;
                desc[tid][p * 4 + c] = make_uint2(addr, __float_as_uint(wgt));
            }
        }
    }
    __syncthreads();

    const int rh = tid >> 2;                   // 0..63
    const int q  = tid & 3;                    // 8-channel slice
    const int rhg = rh0 + rh;
    const int h = rhg & 7, rn = rhg >> 3;

    float a[8];
    #pragma unroll
    for (int e = 0; e < 8; ++e) a[e] = 0.f;
    #pragma unroll
    for (int k = 0; k < 16; ++k) {
        uint2 d = desc[rh][k];
        float wgt = __uint_as_float(d.y);
        u16x8 v = *(const u16x8*)(val + d.x + q * 8);
        #pragma unroll
        for (int e = 0; e < 8; ++e)
            a[e] += wgt * bf2f(v[e]);
    }
    u16x8 o;
    #pragma unroll
    for (int e = 0; e < 8; ++e) o[e] = f2bf(a[e]);
    *(u16x8*)(outp + (size_t)rn * CCn + h * 32 + q * 8) = o;
}

// ---------------------------------------------------------------------------
extern "C" void kernel_launch(void* const* d_in, const int* in_sizes, int n_in,
                              void* d_out, int out_size, void* d_ws, size_t ws_size,
                              hipStream_t stream)
{
    const float* cam_bev   = (const float*)d_in[0];
    const float* sat_bev   = (const float*)d_in[1];
    const float* c2s_off_w  = (const float*)d_in[2];
    const float* c2s_off_b  = (const float*)d_in[3];
    const float* c2s_attw_w = (const float*)d_in[4];
    const float* c2s_attw_b = (const float*)d_in[5];
    const float* c2s_vp_w   = (const float*)d_in[6];
    const float* c2s_vp_b   = (const float*)d_in[7];
    const float* c2s_op_w   = (const float*)d_in[8];
    const float* c2s_op_b   = (const float*)d_in[9];
    const float* s2c_off_w  = (const float*)d_in[10];
    const float* s2c_off_b  = (const float*)d_in[11];
    const float* s2c_attw_w = (const float*)d_in[12];
    const float* s2c_attw_b = (const float*)d_in[13];
    const float* s2c_vp_w   = (const float*)d_in[14];
    const float* s2c_vp_b   = (const float*)d_in[15];
    const float* s2c_op_w   = (const float*)d_in[16];
    const float* s2c_op_b   = (const float*)d_in[17];
    const float* ln1_g = (const float*)d_in[18];
    const float* ln1_b = (const float*)d_in[19];
    const float* ln2_g = (const float*)d_in[20];
    const float* ln2_b = (const float*)d_in[21];
    const float* lnf_g = (const float*)d_in[22];
    const float* lnf_b = (const float*)d_in[23];
    const float* ffn1_w = (const float*)d_in[24];
    const float* ffn1_b = (const float*)d_in[25];
    const float* ffn2_w = (const float*)d_in[26];
    const float* ffn2_b = (const float*)d_in[27];
    const float* g1_w  = (const float*)d_in[28];
    const float* bn_g  = (const float*)d_in[29];
    const float* bn_b  = (const float*)d_in[30];
    const float* g2_w  = (const float*)d_in[31];
    const float* g2_b  = (const float*)d_in[32];

    char* base = (char*)d_ws;
    size_t off = 0;
    auto alloc = [&](size_t bytes) -> void* {
        void* p = base + off;
        off += (bytes + 255) & ~(size_t)255;
        return p;
    };

    u16*   qcam   = (u16*)  alloc((size_t)MTOT * CCn * 2 * 2);   // qcam|qsat contiguous
    u16*   qsat   = qcam + (size_t)MTOT * CCn;
    u16*   valb   = (u16*)  alloc((size_t)MTOT * CCn * 2 * 2);   // pair
    u16*   sampb  = (u16*)  alloc((size_t)MTOT * CCn * 2 * 2);   // pair (33.55MB)
    float* offb   = (float*)alloc((size_t)MTOT * 64 * 4 * 2);    // pair (16.78MB)
    float* attwb  = (float*)alloc((size_t)MTOT * 32 * 4 * 2);    // pair
    size_t padBytes = (size_t)BBn * PADW * PADW * 512 * 2;       // 34.6MB
    u16*   pad    = (u16*)  alloc(padBytes);
    u16*   hbuf   = (u16*)  alloc((size_t)MTOT * 128 * 2);
    u16*   convpart = (u16*)alloc((size_t)3 * MTOT * 128 * 2);   // 25.2MB
    u16*   wbase  = (u16*)  alloc((size_t)1212416 * 2);
    float* biasbf = (float*)alloc((size_t)2240 * 4);
    // weight slices
    u16* wvp = wbase;                 // pair, stride 65536
    u16* wop = wbase + 131072;        // pair, stride 65536
    u16* wf1 = wbase + 262144;
    u16* wf2 = wbase + 393216;
    u16* woa = wbase + 524288;        // pair, stride 32768
    u16* wcv = wbase + 589824;
    u16* wg2 = wbase + 1179648;
    // aliases (temporally disjoint)
    u16*   fused_bf = valb;              // valb dead after sampling
    u16*   midb     = qcam;              // qcam/qsat dead after op-pair (MTOT*512 bf16)

    dim3 blk(256);
    ZOff zz{0, 0, 0, 0, 0, 0, 0, 0, 0};

    // ---------- fused prologue: tcvt | repack | zring ----------
    prologue_k<<<9100, blk, 0, stream>>>(
        cam_bev, sat_bev, qcam, qsat,
        c2s_vp_w, c2s_op_w, s2c_vp_w, s2c_op_w,
        ffn1_w, ffn2_w, c2s_off_w, c2s_attw_w,
        s2c_off_w, s2c_attw_w, g1_w, g2_w,
        c2s_vp_b, s2c_vp_b, c2s_op_b, s2c_op_b,
        c2s_off_b, c2s_attw_b, s2c_off_b, s2c_attw_b,
        ln1_g, ln1_b, ln2_g, ln2_b,
        wbase, biasbf, pad);

    // ---------- fused value + offset/attw projections ----------
    vpoa_k<<<1536, blk, 0, stream>>>(qcam, wvp, woa, biasbf, valb, offb, attwb);

    // ---------- deformable sampling (2-phase, 16B gathers, XCD-chunked) ----
    sample_k<<<dim3(4096, 1, 2), blk, 0, stream>>>(valb, offb, attwb, sampb);
    // ---------- output projections + residual + LN -> pad image ----------
    {
        ZOff zo{ (long)MTOT * CCn, 65536, 256, 0, 0, 0, (long)MTOT * CCn, 512, 256 };
        mgemm<64, 256, 4, 7, 256><<<dim3(1, 512, 2), blk, 0, stream>>>(
            sampb, wop, biasbf + 512, 256, 256,
            nullptr, nullptr, pad, nullptr, qcam, biasbf + 1216, biasbf + 1472, 0, zo);
    }
    // ---------- gating conv: BK=32 dbuf, split-K=3, bf16 partials ----------
    conv_k<3><<<dim3(1, 256, 3), blk, 0, stream>>>(pad, wcv, convpart);
    combine_k<<<4096, blk, 0, stream>>>(convpart, bn_g, bn_b, hbuf);

    // ---------- 1x1 conv + sigmoid + gated fusion (bf16 out, BM=64) ----------
    mgemm<64, 128, 2, 4, 128><<<dim3(2, 512, 1), blk, 0, stream>>>(
        hbuf, wg2, g2_b, 128, 256,
        nullptr, nullptr, fused_bf, pad, nullptr, nullptr, nullptr, 0, zz);

    // ---------- FFN ----------
    mgemm<128, 128, 2, 5, 256><<<dim3(4, 256, 1), blk, 0, stream>>>(
        fused_bf, wf1, ffn1_b, 256, 512,
        nullptr, nullptr, midb, nullptr, nullptr, nullptr, nullptr, 0, zz);
    // ffn2 + final LN + transpose to (B,C,N) + cam residual (EPI 9, bf16 resid)
    mgemm<64, 256, 4, 9, 512><<<dim3(1, 512, 1), blk, 0, stream>>>(
        midb, wf2, ffn2_b, 512, 256,
        (float*)d_out, (float*)cam_bev, nullptr, nullptr, fused_bf, lnf_g, lnf_b, 0, zz);
}